// Round 14
// baseline (1810.925 us; speedup 1.0000x reference)
//
#include <hip/hip_runtime.h>
#include <math.h>

#define Bg 32
#define Ng 2048
#define Kn 20
#define BNn (Bg*Ng)
#define En (BNn*Kn)
#define Hd 64
#define Cd 40

// knn-mfma params
#define KK 24            // approx top-K kept per j-quarter (96 cands/row)

typedef __attribute__((ext_vector_type(8))) short bf16x8;
typedef __attribute__((ext_vector_type(4))) float f32x4;

__device__ __forceinline__ unsigned enc_f32(float f){
  unsigned u = __float_as_uint(f);
  return ((int)u < 0) ? ~u : (u | 0x80000000u);
}

__device__ __forceinline__ unsigned short bf16rne(float f){
  unsigned u = __float_as_uint(f);
  return (unsigned short)((u + 0x7FFFu + ((u >> 16) & 1u)) >> 16);
}

// ---------- weight prep
__global__ void prep_w_kernel(const float* __restrict__ w1c, const float* __restrict__ w1d1,
                              const float* __restrict__ w1d2,
                              float* __restrict__ wpq0, float* __restrict__ wpq1,
                              float* __restrict__ wpq2){
  int t = blockIdx.x*256 + threadIdx.x;
  if (t < 3*128){
    int d = t >> 7, l = t & 127;
    wpq0[t] = (l < 64) ? (w1c[d*64 + l] - w1c[(d+3)*64 + l]) : w1c[(d+3)*64 + (l-64)];
  }
  if (t < 64*128){
    int d = t >> 7, l = t & 127;
    wpq1[t] = (l < 64) ? (w1d1[d*64 + l] - w1d1[(d+64)*64 + l]) : w1d1[(d+64)*64 + (l-64)];
    wpq2[t] = (l < 64) ? (w1d2[d*64 + l] - w1d2[(d+64)*64 + l]) : w1d2[(d+64)*64 + (l-64)];
  }
}

__global__ void zero_kernel(int* __restrict__ p){
  p[blockIdx.x*256 + threadIdx.x] = 0;
}

__global__ void init_enc_kernel(unsigned int* __restrict__ enc){
  enc[blockIdx.x*256 + threadIdx.x] = 0x007FFFFFu;   // enc(-inf)
}

// ---------- X[BN,D] @ wpq[D,128] -> P,Q
template<int D>
__global__ __launch_bounds__(128) void gemm_pq_kernel(const float* __restrict__ x,
                               const float* __restrict__ w,
                               float* __restrict__ P, float* __restrict__ Q){
  __shared__ float xs[8*D];
  int l = threadIdx.x;
  int node0 = blockIdx.x*8;
  float wc[D];
  #pragma unroll
  for (int d=0; d<D; d++) wc[d] = w[d*128 + l];
  for (int i=l; i < 8*D; i += 128) xs[i] = x[(size_t)node0*D + i];
  __syncthreads();
  #pragma unroll
  for (int n=0; n<8; n++){
    float s = 0.f;
    #pragma unroll
    for (int d=0; d<D; d++) s = fmaf(xs[n*D+d], wc[d], s);
    int node = node0 + n;
    if (l < 64) P[(size_t)node*64 + l] = s;
    else        Q[(size_t)node*64 + (l-64)] = s;
  }
}

// ---------- sq norms + bf16 copy of X (first static layer input path)
__global__ __launch_bounds__(256) void sqxb_kernel(const float* __restrict__ x,
        float* __restrict__ sq, unsigned short* __restrict__ xb){
  int t = blockIdx.x*256 + threadIdx.x;
  int node = t >> 6, l = t & 63;
  float v = x[t];
  xb[t] = bf16rne(v);
  float s = v*v;
  #pragma unroll
  for (int o=32; o; o>>=1) s += __shfl_xor(s, o, 64);
  if (l == 0) sq[node] = s;
}

// ---------- fused decode(+b2,+ELU) -> X, bf16 XB, SQ
__global__ __launch_bounds__(256) void decode_sqxb_kernel(const unsigned int* __restrict__ enc,
        const float* __restrict__ b2, float* __restrict__ x,
        float* __restrict__ sq, unsigned short* __restrict__ xb){
  int t = blockIdx.x*256 + threadIdx.x;
  int node = t >> 6, l = t & 63;
  unsigned int e = enc[t];
  unsigned int bits = (e & 0x80000000u) ? (e ^ 0x80000000u) : ~e;
  float f = __uint_as_float(bits);
  if (isfinite(f)) f += b2[l]; else f = 0.f;
  f = f > 0.f ? f : expm1f(f);
  x[t] = f;
  xb[t] = bf16rne(f);
  float s = f*f;
  #pragma unroll
  for (int o=32; o; o>>=1) s += __shfl_xor(s, o, 64);
  if (l == 0) sq[node] = s;
}

// ---------- CSR build
__global__ void count_kernel(const int* __restrict__ ei, int* __restrict__ deg){
  int e = blockIdx.x*256 + threadIdx.x;
  atomicAdd(&deg[ei[En + e]], 1);
}

__global__ __launch_bounds__(1024) void scan_kernel(const int* __restrict__ deg,
        int* __restrict__ rowptr, int* __restrict__ cursor){
  __shared__ int ps[1024];
  int t = threadIdx.x;
  int base = t*64;
  int s = 0;
  for (int k=0;k<64;k++) s += deg[base+k];
  ps[t] = s; __syncthreads();
  for (int off=1; off<1024; off<<=1){
    int v = (t>=off) ? ps[t-off] : 0;
    __syncthreads();
    ps[t] += v;
    __syncthreads();
  }
  int run = (t>0) ? ps[t-1] : 0;
  for (int k=0;k<64;k++){
    rowptr[base+k] = run; cursor[base+k] = run;
    run += deg[base+k];
  }
  if (t==1023) rowptr[BNn] = run;
}

__global__ void scatter_kernel(const int* __restrict__ ei, int* __restrict__ cursor,
                               int* __restrict__ csrc, int* __restrict__ enid){
  int e = blockIdx.x*256 + threadIdx.x;
  int s = ei[e], d = ei[En + e];
  int pos = atomicAdd(&cursor[d], 1);
  csrc[pos] = s;
  enid[pos] = d;
}

// swizzled LDS address: row-major [*][stride bytes], byte ^= (row&7)<<4
#define SWZ16(base, row, stridep2, byteoff) \
  ((unsigned short*)((char*)(base) + ((((row) << (stridep2)) + (byteoff)) ^ (((row) & 7) << 4))))

// ---------- static EdgeConv v2: split-bf16 MFMA GEMM + Ct-LDS run-max epilogue
__global__ __launch_bounds__(256,3) void econv_gemm_kernel(
    const int* __restrict__ csrc, const int* __restrict__ enid,
    const float* __restrict__ P, const float* __restrict__ Q,
    const float* __restrict__ b1, const float* __restrict__ w2,
    unsigned int* __restrict__ enc){
  __shared__ __align__(16) char smem[49152];
  unsigned short* Ah = (unsigned short*)smem;            // [128][64] bf16 swz, 16384
  unsigned short* Al = (unsigned short*)(smem + 16384);  // 16384
  unsigned short* Wh = (unsigned short*)(smem + 32768);  // [64 n][64 k] bf16 swz, 8192
  unsigned short* Wl = (unsigned short*)(smem + 40960);  // 8192
  float* Ct = (float*)smem;                              // [64 ch][128 row] f32 overlay
  __shared__ int eids[256];
  int tid = threadIdx.x;
  int lane = tid & 63, w = tid >> 6;
  int e0 = ((blockIdx.x & 7)*640 + (blockIdx.x >> 3))*256;   // XCD-chunked (5120 wg)

  eids[tid] = enid[e0 + tid];
  // ---- stage W2 hi/lo transposed [n][k]
  #pragma unroll
  for (int z = 0; z < 16; z++){
    int idx = z*256 + tid;
    int k = idx >> 6, n = idx & 63;
    float f = w2[idx];
    unsigned short h = bf16rne(f);
    float fh = __uint_as_float((unsigned)h << 16);
    unsigned short l = bf16rne(f - fh);
    *SWZ16(Wh, n, 7, k*2) = h;
    *SWZ16(Wl, n, 7, k*2) = l;
  }

  #pragma unroll 1
  for (int hh = 0; hh < 2; hh++){
    int eh0 = e0 + hh*128;
    __syncthreads();          // prev-half Ct reads done; eids/W visible (hh=0)
    // ---- stage A = relu(P[i]+Q[j]+b1) -> bf16 hi/lo
    {
      int el = tid >> 1, kh2 = (tid & 1) * 32;
      int e = eh0 + el;
      int i = eids[hh*128 + el];
      int j = csrc[e];
      const float* Pr = P + (size_t)i*Hd + kh2;
      const float* Qr = Q + (size_t)j*Hd + kh2;
      const float* Br = b1 + kh2;
      #pragma unroll
      for (int m = 0; m < 4; m++){
        float4 pa = ((const float4*)Pr)[2*m], pb = ((const float4*)Pr)[2*m+1];
        float4 qa = ((const float4*)Qr)[2*m], qb = ((const float4*)Qr)[2*m+1];
        float4 ba = ((const float4*)Br)[2*m], bbv = ((const float4*)Br)[2*m+1];
        float a[8];
        a[0]=fmaxf(pa.x+qa.x+ba.x,0.f);  a[1]=fmaxf(pa.y+qa.y+ba.y,0.f);
        a[2]=fmaxf(pa.z+qa.z+ba.z,0.f);  a[3]=fmaxf(pa.w+qa.w+ba.w,0.f);
        a[4]=fmaxf(pb.x+qb.x+bbv.x,0.f); a[5]=fmaxf(pb.y+qb.y+bbv.y,0.f);
        a[6]=fmaxf(pb.z+qb.z+bbv.z,0.f); a[7]=fmaxf(pb.w+qb.w+bbv.w,0.f);
        unsigned hw[4], lw[4];
        #pragma unroll
        for (int t=0;t<4;t++){
          unsigned short h0 = bf16rne(a[2*t]);
          unsigned short h1 = bf16rne(a[2*t+1]);
          float f0 = __uint_as_float((unsigned)h0 << 16);
          float f1 = __uint_as_float((unsigned)h1 << 16);
          unsigned short l0 = bf16rne(a[2*t] - f0);
          unsigned short l1 = bf16rne(a[2*t+1] - f1);
          hw[t] = (unsigned)h0 | ((unsigned)h1 << 16);
          lw[t] = (unsigned)l0 | ((unsigned)l1 << 16);
        }
        uint4 hv = {hw[0], hw[1], hw[2], hw[3]};
        uint4 lv = {lw[0], lw[1], lw[2], lw[3]};
        *(uint4*)SWZ16(Ah, el, 7, (kh2 + 8*m)*2) = hv;
        *(uint4*)SWZ16(Al, el, 7, (kh2 + 8*m)*2) = lv;
      }
    }
    __syncthreads();
    // ---- MFMA: wave w computes rows [w*32, w*32+32) x 64 cols
    bf16x8 Af[2][2], Lf[2][2];
    #pragma unroll
    for (int mt=0; mt<2; mt++)
      #pragma unroll
      for (int s=0; s<2; s++){
        int row = w*32 + mt*16 + (lane & 15);
        Af[mt][s] = *(const bf16x8*)SWZ16(Ah, row, 7, (s*32 + (lane>>4)*8)*2);
        Lf[mt][s] = *(const bf16x8*)SWZ16(Al, row, 7, (s*32 + (lane>>4)*8)*2);
      }
    f32x4 acc[2][4];
    #pragma unroll
    for (int mt=0; mt<2; mt++)
      #pragma unroll
      for (int nt=0; nt<4; nt++)
        acc[mt][nt] = (f32x4){0.f,0.f,0.f,0.f};
    #pragma unroll
    for (int nt=0; nt<4; nt++){
      int n = nt*16 + (lane & 15);
      bf16x8 Bh0 = *(const bf16x8*)SWZ16(Wh, n, 7, ((lane>>4)*8)*2);
      bf16x8 Bh1 = *(const bf16x8*)SWZ16(Wh, n, 7, (32 + (lane>>4)*8)*2);
      bf16x8 Bl0 = *(const bf16x8*)SWZ16(Wl, n, 7, ((lane>>4)*8)*2);
      bf16x8 Bl1 = *(const bf16x8*)SWZ16(Wl, n, 7, (32 + (lane>>4)*8)*2);
      #pragma unroll
      for (int mt=0; mt<2; mt++){
        f32x4 a_ = acc[mt][nt];
        a_ = __builtin_amdgcn_mfma_f32_16x16x32_bf16(Af[mt][0], Bh0, a_, 0, 0, 0);
        a_ = __builtin_amdgcn_mfma_f32_16x16x32_bf16(Af[mt][1], Bh1, a_, 0, 0, 0);
        a_ = __builtin_amdgcn_mfma_f32_16x16x32_bf16(Af[mt][0], Bl0, a_, 0, 0, 0);
        a_ = __builtin_amdgcn_mfma_f32_16x16x32_bf16(Af[mt][1], Bl1, a_, 0, 0, 0);
        a_ = __builtin_amdgcn_mfma_f32_16x16x32_bf16(Lf[mt][0], Bh0, a_, 0, 0, 0);
        a_ = __builtin_amdgcn_mfma_f32_16x16x32_bf16(Lf[mt][1], Bh1, a_, 0, 0, 0);
        acc[mt][nt] = a_;
      }
    }
    __syncthreads();          // Ah/Al dead -> Ct overlay
    // ---- write C^T to LDS (swizzled)
    #pragma unroll
    for (int mt=0; mt<2; mt++){
      int rb = w*32 + mt*16 + (lane>>4)*4;
      #pragma unroll
      for (int nt=0; nt<4; nt++){
        int ch = nt*16 + (lane & 15);
        #pragma unroll
        for (int v=0; v<4; v++)
          Ct[ch*128 + ((rb+v) ^ (ch & 31))] = acc[mt][nt][v];
      }
    }
    __syncthreads();
    // ---- epilogue: per (ch, 32-row part) run-max over eids -> atomicMax(enc)
    {
      int ch = tid & 63, part = tid >> 6;
      int rbase = part*32;
      int cur = eids[hh*128 + rbase];
      float vmax = -INFINITY;
      #pragma unroll 1
      for (int r = 0; r < 32; r++){
        int row = rbase + r;
        int id = eids[hh*128 + row];
        float v = Ct[ch*128 + (row ^ (ch & 31))];
        if (id != cur){
          atomicMax(&enc[(size_t)cur*Hd + ch], enc_f32(vmax));
          vmax = -INFINITY; cur = id;
        }
        vmax = fmaxf(vmax, v);
      }
      atomicMax(&enc[(size_t)cur*Hd + ch], enc_f32(vmax));
    }
  }
}

// ---------- kNN: bf16-MFMA approx distances + per-quarter top-24 (u32 keys)
// v12 (R13, kept): registerized pending + merge-flush + bitonic warm-start.
#define KNN_MFLUSH(bm) do { \
  unsigned Lm[32]; \
  _Pragma("unroll") \
  for (int t=0;t<KK;t++) Lm[t] = kb[t]; \
  _Pragma("unroll") \
  for (int k2=2;k2<=8;k2<<=1) \
    _Pragma("unroll") \
    for (int j2=k2>>1;j2>0;j2>>=1) \
      _Pragma("unroll") \
      for (int i2=0;i2<8;i2++){ \
        int ixj=i2^j2; \
        if (ixj>i2){ \
          unsigned a=bm[i2], c=bm[ixj]; \
          unsigned lo = a<c?a:c, hi = a<c?c:a; \
          bool up = ((i2 & k2)==0); \
          bm[i2] = up?lo:hi; bm[ixj] = up?hi:lo; \
        } \
      } \
  _Pragma("unroll") \
  for (int t=0;t<8;t++) Lm[24+t] = bm[7-t]; \
  _Pragma("unroll") \
  for (int j2=16;j2>0;j2>>=1) \
    _Pragma("unroll") \
    for (int i2=0;i2<32;i2++){ \
      int ixj=i2^j2; \
      if (ixj>i2){ \
        unsigned a=Lm[i2], c=Lm[ixj]; \
        Lm[i2] = a<c?a:c; Lm[ixj] = a<c?c:a; \
      } \
    } \
  _Pragma("unroll") \
  for (int t=0;t<KK;t++) kb[t] = Lm[t]; \
  kbLast = kb[KK-1]; \
} while(0)

__global__ __launch_bounds__(256,4) void knn_kernel(
    const unsigned short* __restrict__ xb, const float* __restrict__ sq,
    unsigned short* __restrict__ cand){
  __shared__ __align__(16) unsigned short xjb[128*64];    // 16384 B (swizzled)
  __shared__ __align__(16) unsigned short Dt[64*128];     // 16384 B (u16 keys, swizzled)
  __shared__ float sqs[128];                              // 512 B  => 33280 B total

  int tid = threadIdx.x;
  int lane = tid & 63, w = tid >> 6;
  int bid = ((blockIdx.x & 7) << 7) | (blockIdx.x >> 3);  // XCD-chunked (1024 wg)
  int g  = bid >> 5;
  int r0 = (bid & 31) * 64;
  const unsigned short* xbg = xb + (size_t)g*Ng*Hd;
  const float* sg = sq + (size_t)g*Ng;

  int q = w;
  int prow = lane;
  int rw = w*16;

  // ---- A fragments direct from global (rows are L2-hot; no LDS staging)
  bf16x8 A0, A1;
  {
    int arow = r0 + rw + (lane & 15);
    A0 = *(const bf16x8*)(xbg + (size_t)arow*Hd +      (lane>>4)*8);
    A1 = *(const bf16x8*)(xbg + (size_t)arow*Hd + 32 + (lane>>4)*8);
  }
  // ---- stage xjb (swizzled) + sqs
  {
    int jr = tid >> 1, half = tid & 1;
    int jloc = (jr >> 5)*512 + (jr & 31);
    const uint4* src = (const uint4*)(xbg + (size_t)jloc*Hd + half*32);
    uint4 a = src[0], b = src[1], c2 = src[2], d2 = src[3];
    *(uint4*)SWZ16(xjb, jr, 7, half*64 +  0) = a;
    *(uint4*)SWZ16(xjb, jr, 7, half*64 + 16) = b;
    *(uint4*)SWZ16(xjb, jr, 7, half*64 + 32) = c2;
    *(uint4*)SWZ16(xjb, jr, 7, half*64 + 48) = d2;
    if (tid < 128) sqs[tid] = sg[(tid>>5)*512 + (tid&31)];
  }

  unsigned kb[KK];
  #pragma unroll
  for (int t=0;t<KK;t++) kb[t] = 0xFFFFFFFFu;
  unsigned kbLast = 0xFFFFFFFFu;

  __syncthreads();

  #pragma unroll 1
  for (int it = 0; it < 16; it++){
    uint4 pf0, pf1, pf2, pf3; float psq = 0.f;
    int itn = it + 1;
    int jr = tid >> 1, half = tid & 1;
    if (itn < 16){
      int jloc = (jr >> 5)*512 + itn*32 + (jr & 31);
      const uint4* src = (const uint4*)(xbg + (size_t)jloc*Hd + half*32);
      pf0 = src[0]; pf1 = src[1]; pf2 = src[2]; pf3 = src[3];
      if (tid < 128) psq = sg[(tid>>5)*512 + itn*32 + (tid&31)];
    }
    #pragma unroll
    for (int jb = 0; jb < 8; jb++){
      int brow = jb*16 + (lane & 15);
      bf16x8 B0 = *(const bf16x8*)SWZ16(xjb, brow, 7,      (lane>>4)*16);
      bf16x8 B1 = *(const bf16x8*)SWZ16(xjb, brow, 7, 64 + (lane>>4)*16);
      f32x4 acc = {0.f, 0.f, 0.f, 0.f};
      acc = __builtin_amdgcn_mfma_f32_16x16x32_bf16(A0, B0, acc, 0, 0, 0);
      acc = __builtin_amdgcn_mfma_f32_16x16x32_bf16(A1, B1, acc, 0, 0, 0);
      int col = jb*16 + (lane & 15);
      float sqv = sqs[col];
      int rbase = rw + (lane>>4)*4;
      #pragma unroll
      for (int v=0; v<4; v++){
        // sortable u16 encode of f = -2*dot + sqj  (top 16 bits of sign-flipped f32)
        float f = fmaf(acc[v], -2.f, sqv);
        unsigned u = __float_as_uint(f);
        unsigned t2 = ((unsigned)((int)u >> 31)) | 0x8000u;
        *SWZ16(Dt, rbase + v, 8, col*2) = (unsigned short)((u >> 16) ^ t2);
      }
    }
    __syncthreads();
    if (it == 0){
      // warm start: sort this lane's 32 keys (bitonic, registers), kb = smallest 24
      unsigned key[32];
      const char* dbase = (const char*)Dt + (prow << 8);
      unsigned m = (prow & 7) << 4;
      #pragma unroll
      for (int r4=0; r4<4; r4++){
        uint4 dv = *(const uint4*)(dbase + ((unsigned)(q*64 + r4*16) ^ m));
        int cb = q*512 + r4*8;
        key[r4*8+0] = (dv.x << 16) + (unsigned)(cb + 0);
        key[r4*8+1] = (dv.x & 0xFFFF0000u) | (unsigned)(cb + 1);
        key[r4*8+2] = (dv.y << 16) + (unsigned)(cb + 2);
        key[r4*8+3] = (dv.y & 0xFFFF0000u) | (unsigned)(cb + 3);
        key[r4*8+4] = (dv.z << 16) + (unsigned)(cb + 4);
        key[r4*8+5] = (dv.z & 0xFFFF0000u) | (unsigned)(cb + 5);
        key[r4*8+6] = (dv.w << 16) + (unsigned)(cb + 6);
        key[r4*8+7] = (dv.w & 0xFFFF0000u) | (unsigned)(cb + 7);
      }
      #pragma unroll
      for (int k2 = 2; k2 <= 32; k2 <<= 1){
        #pragma unroll
        for (int j2 = k2>>1; j2 > 0; j2 >>= 1){
          #pragma unroll
          for (int i2 = 0; i2 < 32; i2++){
            int ixj = i2 ^ j2;
            if (ixj > i2){
              unsigned a = key[i2], b = key[ixj];
              unsigned lo = a < b ? a : b;
              unsigned hi = a < b ? b : a;
              bool up = ((i2 & k2) == 0);
              key[i2]  = up ? lo : hi;
              key[ixj] = up ? hi : lo;
            }
          }
        }
      }
      #pragma unroll
      for (int t=0;t<KK;t++) kb[t] = key[t];
      kbLast = kb[KK-1];
    } else {
      int jbase0 = q*512 + it*32;
      const char* dbase = (const char*)Dt + (prow << 8);
      unsigned m = (prow & 7) << 4;
      #pragma unroll
      for (int r4=0; r4<4; r4++){
        uint4 dv = *(const uint4*)(dbase + ((unsigned)(q*64 + r4*16) ^ m));
        int cb = jbase0 + r4*8;
        unsigned k0 = (dv.x << 16) + (unsigned)(cb + 0);
        unsigned k1 = (dv.x & 0xFFFF0000u) | (unsigned)(cb + 1);
        unsigned k2v = (dv.y << 16) + (unsigned)(cb + 2);
        unsigned k3 = (dv.y & 0xFFFF0000u) | (unsigned)(cb + 3);
        unsigned k4 = (dv.z << 16) + (unsigned)(cb + 4);
        unsigned k5 = (dv.z & 0xFFFF0000u) | (unsigned)(cb + 5);
        unsigned k6 = (dv.w << 16) + (unsigned)(cb + 6);
        unsigned k7 = (dv.w & 0xFFFF0000u) | (unsigned)(cb + 7);
        unsigned bm[8];
        bm[0] = (k0 < kbLast) ? k0 : 0xFFFFFFFFu;
        bm[1] = (k1 < kbLast) ? k1 : 0xFFFFFFFFu;
        bm[2] = (k2v < kbLast) ? k2v : 0xFFFFFFFFu;
        bm[3] = (k3 < kbLast) ? k3 : 0xFFFFFFFFu;
        bm[4] = (k4 < kbLast) ? k4 : 0xFFFFFFFFu;
        bm[5] = (k5 < kbLast) ? k5 : 0xFFFFFFFFu;
        bm[6] = (k6 < kbLast) ? k6 : 0xFFFFFFFFu;
        bm[7] = (k7 < kbLast) ? k7 : 0xFFFFFFFFu;
        unsigned mn01 = bm[0] < bm[1] ? bm[0] : bm[1];
        unsigned mn23 = bm[2] < bm[3] ? bm[2] : bm[3];
        unsigned mn45 = bm[4] < bm[5] ? bm[4] : bm[5];
        unsigned mn67 = bm[6] < bm[7] ? bm[6] : bm[7];
        unsigned mn03 = mn01 < mn23 ? mn01 : mn23;
        unsigned mn47 = mn45 < mn67 ? mn45 : mn67;
        unsigned mn = mn03 < mn47 ? mn03 : mn47;
        if (__any(mn != 0xFFFFFFFFu)) KNN_MFLUSH(bm);
      }
    }
    if (itn < 16){
      *(uint4*)SWZ16(xjb, jr, 7, half*64 +  0) = pf0;
      *(uint4*)SWZ16(xjb, jr, 7, half*64 + 16) = pf1;
      *(uint4*)SWZ16(xjb, jr, 7, half*64 + 32) = pf2;
      *(uint4*)SWZ16(xjb, jr, 7, half*64 + 48) = pf3;
      if (tid < 128) sqs[tid] = psq;
    }
    __syncthreads();
  }
  size_t base = (size_t)(g*Ng + r0 + prow)*96 + q*24;
  #pragma unroll
  for (int t=0;t<KK;t++)
    cand[base + t] = (unsigned short)(kb[t] & 2047u);
}

// ---------- exact rerank v6: two-batch gather pipeline (3 cands in flight)
//   R13's all-24-in-flight cost 104 VGPR -> 4 waves/SIMD. Batches of 3
//   (bb[3][4]=48 regs live) drop VGPR to ~80 -> 6 waves/SIMD; per-thread MLP
//   halves but aggregate outstanding loads/CU rises with wave count.
//   Identical arithmetic, reordered loads -> bit-identical.
__global__ __launch_bounds__(256,4) void rerank_kernel(const float* __restrict__ x,
        const unsigned short* __restrict__ cand, int* __restrict__ idx){
  __shared__ __align__(16) unsigned long long ks[4][96];
  int tid = threadIdx.x;
  int lane = tid & 63, w = tid >> 6;
  int bid = ((blockIdx.x & 7) << 11) | (blockIdx.x >> 3);   // XCD-chunked (16384 wg)
  int row = bid*4 + w;
  int g = row >> 11;
  const float* xg = x + (size_t)g*Ng*Hd;
  int chunk = lane & 3;        // 16B chunk within a row
  int cg = lane >> 2;          // candidate group 0..15
  const float* xr = x + (size_t)row*Hd;
  float4 xc[4];
  #pragma unroll
  for (int it2=0; it2<4; it2++) xc[it2] = *(const float4*)(xr + 16*it2 + 4*chunk);

  int js[6];
  #pragma unroll
  for (int p=0; p<6; p++) js[p] = cand[(size_t)row*96 + p*16 + cg];

  #pragma unroll
  for (int b=0; b<2; b++){
    float4 bb[3][4];
    #pragma unroll
    for (int p=0; p<3; p++){
      const float* xj = xg + (size_t)js[b*3+p]*Hd;
      #pragma unroll
      for (int it2=0; it2<4; it2++) bb[p][it2] = *(const float4*)(xj + 16*it2 + 4*chunk);
    }
    #pragma unroll
    for (int p=0; p<3; p++){
      float dot = 0.f, sqj = 0.f;
      #pragma unroll
      for (int it2=0; it2<4; it2++){
        float4 bv = bb[p][it2];
        float4 a = xc[it2];
        dot = fmaf(a.x, bv.x, dot); dot = fmaf(a.y, bv.y, dot);
        dot = fmaf(a.z, bv.z, dot); dot = fmaf(a.w, bv.w, dot);
        sqj = fmaf(bv.x, bv.x, sqj); sqj = fmaf(bv.y, bv.y, sqj);
        sqj = fmaf(bv.z, bv.z, sqj); sqj = fmaf(bv.w, bv.w, sqj);
      }
      dot += __shfl_xor(dot, 1, 64); dot += __shfl_xor(dot, 2, 64);
      sqj += __shfl_xor(sqj, 1, 64); sqj += __shfl_xor(sqj, 2, 64);
      if (chunk == 0){
        float dist = fmaf(dot, -2.f, sqj);   // row-constant +sq_i dropped (order-invariant)
        ks[w][(b*3+p)*16 + cg] = ((unsigned long long)enc_f32(dist) << 32) | (unsigned)js[b*3+p];
      }
    }
  }
  __syncthreads();
  unsigned long long k0 = ks[w][lane];
  unsigned long long k1 = (lane < 32) ? ks[w][64 + lane] : ~0ULL;
  int r0 = 0, r1 = 0;
  #pragma unroll
  for (int c=0;c<96;c+=2){
    unsigned long long a = ks[w][c], b = ks[w][c+1];
    r0 += (a < k0) + (b < k0);
    r1 += (a < k1) + (b < k1);
  }
  if (r0 < Kn) idx[(size_t)row*Kn + r0] = g*Ng + (int)(k0 & 2047ULL);
  if (lane < 32 && r1 < Kn) idx[(size_t)row*Kn + r1] = g*Ng + (int)(k1 & 2047ULL);
}

// ---------- dynamic EdgeConv stage 2 v2: split-bf16 MFMA GEMM (bf16x3)
__global__ __launch_bounds__(256,3) void emsg_kernel(
    const int* __restrict__ srcl,
    const float* __restrict__ P, const float* __restrict__ Q,
    const float* __restrict__ b1, const float* __restrict__ w2,
    unsigned int* __restrict__ enc){
  __shared__ __align__(16) char smem[49152];
  unsigned short* Ah = (unsigned short*)smem;            // [128][64] bf16 swz, 16384
  unsigned short* Al = (unsigned short*)(smem + 16384);  // 16384
  unsigned short* Wh = (unsigned short*)(smem + 32768);  // [64 n][64 k] bf16 swz, 8192
  unsigned short* Wl = (unsigned short*)(smem + 40960);  // 8192
  float* p0 = (float*)smem;                              // [64][33] f32 overlay on Ah/Al
  float* p1 = (float*)(smem + 8448);
  int tid = threadIdx.x;
  int lane = tid & 63, w = tid >> 6;
  int e0 = ((blockIdx.x & 7)*640 + (blockIdx.x >> 3))*256;   // XCD-chunked (5120 wg)

  // ---- stage W2 hi/lo transposed [n][k] (once; n = tid&63, k = z*4 + tid>>6)
  #pragma unroll
  for (int z = 0; z < 16; z++){
    int idx = z*256 + tid;
    int k = idx >> 6, n = idx & 63;
    float f = w2[idx];
    unsigned short h = bf16rne(f);
    float fh = __uint_as_float((unsigned)h << 16);
    unsigned short l = bf16rne(f - fh);
    *SWZ16(Wh, n, 7, k*2) = h;
    *SWZ16(Wl, n, 7, k*2) = l;
  }

  #pragma unroll 1
  for (int hh = 0; hh < 2; hh++){
    int eh0 = e0 + hh*128;
    __syncthreads();          // prev-half p-reads done; W stage visible
    // ---- stage A = relu(P[i]+Q[j]+b1) -> bf16 hi/lo (thread: edge tid>>1, k-half (tid&1)*32)
    {
      int el = tid >> 1, kh = (tid & 1) * 32;
      int e = eh0 + el;
      int i = e / Kn;
      int j = srcl[e];
      const float* Pr = P + (size_t)i*Hd + kh;
      const float* Qr = Q + (size_t)j*Hd + kh;
      const float* Br = b1 + kh;
      #pragma unroll
      for (int m = 0; m < 4; m++){
        float4 pa = ((const float4*)Pr)[2*m], pb = ((const float4*)Pr)[2*m+1];
        float4 qa = ((const float4*)Qr)[2*m], qb = ((const float4*)Qr)[2*m+1];
        float4 ba = ((const float4*)Br)[2*m], bbv = ((const float4*)Br)[2*m+1];
        float a[8];
        a[0]=fmaxf(pa.x+qa.x+ba.x,0.f);  a[1]=fmaxf(pa.y+qa.y+ba.y,0.f);
        a[2]=fmaxf(pa.z+qa.z+ba.z,0.f);  a[3]=fmaxf(pa.w+qa.w+ba.w,0.f);
        a[4]=fmaxf(pb.x+qb.x+bbv.x,0.f); a[5]=fmaxf(pb.y+qb.y+bbv.y,0.f);
        a[6]=fmaxf(pb.z+qb.z+bbv.z,0.f); a[7]=fmaxf(pb.w+qb.w+bbv.w,0.f);
        unsigned hw[4], lw[4];
        #pragma unroll
        for (int t=0;t<4;t++){
          unsigned short h0 = bf16rne(a[2*t]);
          unsigned short h1 = bf16rne(a[2*t+1]);
          float f0 = __uint_as_float((unsigned)h0 << 16);
          float f1 = __uint_as_float((unsigned)h1 << 16);
          unsigned short l0 = bf16rne(a[2*t] - f0);
          unsigned short l1 = bf16rne(a[2*t+1] - f1);
          hw[t] = (unsigned)h0 | ((unsigned)h1 << 16);
          lw[t] = (unsigned)l0 | ((unsigned)l1 << 16);
        }
        uint4 hv = {hw[0], hw[1], hw[2], hw[3]};
        uint4 lv = {lw[0], lw[1], lw[2], lw[3]};
        *(uint4*)SWZ16(Ah, el, 7, (kh + 8*m)*2) = hv;
        *(uint4*)SWZ16(Al, el, 7, (kh + 8*m)*2) = lv;
      }
    }
    __syncthreads();
    // ---- MFMA: wave w computes rows [w*32, w*32+32) x 64 cols
    bf16x8 Af[2][2], Lf[2][2];
    #pragma unroll
    for (int mt=0; mt<2; mt++)
      #pragma unroll
      for (int s=0; s<2; s++){
        int row = w*32 + mt*16 + (lane & 15);
        Af[mt][s] = *(const bf16x8*)SWZ16(Ah, row, 7, (s*32 + (lane>>4)*8)*2);
        Lf[mt][s] = *(const bf16x8*)SWZ16(Al, row, 7, (s*32 + (lane>>4)*8)*2);
      }
    f32x4 acc[2][4];
    #pragma unroll
    for (int mt=0; mt<2; mt++)
      #pragma unroll
      for (int nt=0; nt<4; nt++)
        acc[mt][nt] = (f32x4){0.f,0.f,0.f,0.f};
    #pragma unroll
    for (int nt=0; nt<4; nt++){
      int n = nt*16 + (lane & 15);
      bf16x8 Bh0 = *(const bf16x8*)SWZ16(Wh, n, 7, ((lane>>4)*8)*2);
      bf16x8 Bh1 = *(const bf16x8*)SWZ16(Wh, n, 7, (32 + (lane>>4)*8)*2);
      bf16x8 Bl0 = *(const bf16x8*)SWZ16(Wl, n, 7, ((lane>>4)*8)*2);
      bf16x8 Bl1 = *(const bf16x8*)SWZ16(Wl, n, 7, (32 + (lane>>4)*8)*2);
      #pragma unroll
      for (int mt=0; mt<2; mt++){
        f32x4 a_ = acc[mt][nt];
        a_ = __builtin_amdgcn_mfma_f32_16x16x32_bf16(Af[mt][0], Bh0, a_, 0, 0, 0);
        a_ = __builtin_amdgcn_mfma_f32_16x16x32_bf16(Af[mt][1], Bh1, a_, 0, 0, 0);
        a_ = __builtin_amdgcn_mfma_f32_16x16x32_bf16(Af[mt][0], Bl0, a_, 0, 0, 0);
        a_ = __builtin_amdgcn_mfma_f32_16x16x32_bf16(Af[mt][1], Bl1, a_, 0, 0, 0);
        a_ = __builtin_amdgcn_mfma_f32_16x16x32_bf16(Lf[mt][0], Bh0, a_, 0, 0, 0);
        a_ = __builtin_amdgcn_mfma_f32_16x16x32_bf16(Lf[mt][1], Bh1, a_, 0, 0, 0);
        acc[mt][nt] = a_;
      }
    }
    __syncthreads();          // Ah/Al dead -> p0/p1 overlay
    // ---- p-writes: 4-row chunks, <=2 nodes per chunk (4 < Kn)
    #pragma unroll
    for (int mt=0; mt<2; mt++){
      int rb = w*32 + mt*16 + (lane>>4)*4;
      int rbg = eh0 + rb;
      int nd0 = rbg / Kn;
      int split = (nd0+1)*Kn - rbg; if (split > 4) split = 4;
      int cm = rb >> 2;
      #pragma unroll
      for (int nt=0; nt<4; nt++){
        int ch = nt*16 + (lane & 15);
        float s0v = -INFINITY, s1v = -INFINITY;
        #pragma unroll
        for (int v=0; v<4; v++){
          float val = acc[mt][nt][v];
          if (v < split) s0v = fmaxf(s0v, val); else s1v = fmaxf(s1v, val);
        }
        p0[ch*33 + cm] = s0v;
        p1[ch*33 + cm] = s1v;
      }
    }
    __syncthreads();
    // ---- reduce + atomicMax
    int nfirst = eh0 / Kn;
    int ncnt = (eh0 + 127) / Kn - nfirst + 1;
    int ch = tid & 63;
    for (int ln = tid >> 6; ln < ncnt; ln += 4){
      int nd = nfirst + ln;
      int glo = nd*Kn;      if (glo < eh0)     glo = eh0;
      int ghi = nd*Kn + Kn; if (ghi > eh0+128) ghi = eh0+128;
      int mlo = (glo - eh0) >> 2, mhi = (ghi - 1 - eh0) >> 2;
      float v = -INFINITY;
      for (int mm = mlo; mm <= mhi; mm++){
        int bn = (eh0 + 4*mm) / Kn;
        if (bn == nd)     v = fmaxf(v, p0[ch*33 + mm]);
        if (bn + 1 == nd) v = fmaxf(v, p1[ch*33 + mm]);
      }
      atomicMax(&enc[(size_t)nd*Hd + ch], enc_f32(v));
    }
  }
}

// ---------- final decode (no ELU): enc -> float + b2
__global__ __launch_bounds__(256) void decode_kernel(const unsigned int* __restrict__ enc,
         const float* __restrict__ b2, float* __restrict__ x){
  int t = blockIdx.x*256 + threadIdx.x;
  unsigned int e = enc[t];
  unsigned int bits = (e & 0x80000000u) ? (e ^ 0x80000000u) : ~e;
  float f = __uint_as_float(bits);
  if (isfinite(f)) f += b2[t & 63]; else f = 0.f;
  x[t] = f;
}

__global__ __launch_bounds__(64) void final_kernel(const float* __restrict__ h,
        const float* __restrict__ w, const float* __restrict__ bias,
        float* __restrict__ out){
  __shared__ float xs[Hd];
  int c = threadIdx.x;
  float wc[Hd];
  float bc = 0.f;
  if (c < Cd){
    #pragma unroll
    for (int d=0; d<Hd; d++) wc[d] = w[d*Cd + c];
    bc = bias[c];
  }
  for (int i = blockIdx.x; i < BNn; i += gridDim.x){
    __syncthreads();
    xs[c] = h[(size_t)i*Hd + c];
    __syncthreads();
    if (c < Cd){
      float s = bc;
      #pragma unroll
      for (int d=0; d<Hd; d++) s = fmaf(xs[d], wc[d], s);
      out[(size_t)i*Cd + c] = s;
    }
  }
}

extern "C" void kernel_launch(void* const* d_in, const int* in_sizes, int n_in,
                              void* d_out, int out_size, void* d_ws, size_t ws_size,
                              hipStream_t stream){
  const float* x0   = (const float*)d_in[0];
  const int*   ei   = (const int*)d_in[1];
  const float* c1w1 = (const float*)d_in[3];
  const float* c1b1 = (const float*)d_in[4];
  const float* c1w2 = (const float*)d_in[5];
  const float* c1b2 = (const float*)d_in[6];
  const float* d1w1 = (const float*)d_in[7];
  const float* d1b1 = (const float*)d_in[8];
  const float* d1w2 = (const float*)d_in[9];
  const float* d1b2 = (const float*)d_in[10];
  const float* d2w1 = (const float*)d_in[11];
  const float* d2b1 = (const float*)d_in[12];
  const float* d2w2 = (const float*)d_in[13];
  const float* d2b2 = (const float*)d_in[14];
  const float* linw = (const float*)d_in[15];
  const float* linb = (const float*)d_in[16];
  float* out = (float*)d_out;

  char* ws = (char*)d_ws;
  size_t off = 0;
  auto alloc = [&](size_t bytes)->char*{
    char* p = ws + off; off += (bytes + 255) & ~(size_t)255; return p;
  };
  float*        X    = (float*)alloc(sizeof(float)*(size_t)BNn*Hd);
  float*        P    = (float*)alloc(sizeof(float)*(size_t)BNn*Hd);
  float*        Q    = (float*)alloc(sizeof(float)*(size_t)BNn*Hd);
  float*        H2   = (float*)alloc(sizeof(float)*(size_t)BNn*Hd);  // aliases XB, ENID
  unsigned int* ENC  = (unsigned int*)alloc(sizeof(unsigned)*(size_t)BNn*Hd); // aliases CAND
  int*          SHRD = (int*)alloc(sizeof(int)*(size_t)En);   // CSRC, later IDX
  int*          DEG  = (int*)alloc(sizeof(int)*BNn);
  int*          RPTR = (int*)alloc(sizeof(int)*(BNn+1));
  int*          CUR  = (int*)alloc(sizeof(int)*BNn);
  float*        SQ   = (float*)alloc(sizeof(float)*BNn);
  float*        WPQ0 = (float*)alloc(sizeof(float)*3*128);
  float*        WPQ1 = (float*)alloc(sizeof(float)*64*128);
  float*        WPQ2 = (float*)alloc(sizeof(float)*64*128);
  int*            CSRC = SHRD;
  int*            IDX  = SHRD;
  int*            ENID = (int*)H2;
  unsigned short* XB   = (unsigned short*)H2;
  unsigned short* CAND = (unsigned short*)ENC;
  (void)ws_size; (void)in_sizes; (void)n_in; (void)out_size;

  // static EdgeConv: CSR sort + edge-batched MFMA GEMM + run-max + fused decode
  prep_w_kernel<<<32, 256, 0, stream>>>(c1w1, d1w1, d2w1, WPQ0, WPQ1, WPQ2);
  zero_kernel<<<BNn/256, 256, 0, stream>>>(DEG);
  count_kernel<<<En/256, 256, 0, stream>>>(ei, DEG);
  gemm_pq_kernel<3><<<BNn/8, 128, 0, stream>>>(x0, WPQ0, P, Q);
  scan_kernel<<<1, 1024, 0, stream>>>(DEG, RPTR, CUR);
  scatter_kernel<<<En/256, 256, 0, stream>>>(ei, CUR, CSRC, ENID);
  init_enc_kernel<<<BNn*Hd/256, 256, 0, stream>>>(ENC);
  econv_gemm_kernel<<<En/256, 256, 0, stream>>>(CSRC, ENID, P, Q, c1b1, c1w2, ENC);
  decode_sqxb_kernel<<<BNn*Hd/256, 256, 0, stream>>>(ENC, c1b2, X, SQ, XB);

  // dynamic layer 1
  gemm_pq_kernel<64><<<BNn/8, 128, 0, stream>>>(X, WPQ1, P, Q);
  knn_kernel<<<Bg*32, 256, 0, stream>>>(XB, SQ, CAND);
  rerank_kernel<<<BNn/4, 256, 0, stream>>>(X, CAND, IDX);
  init_enc_kernel<<<BNn*Hd/256, 256, 0, stream>>>(ENC);
  emsg_kernel<<<En/256, 256, 0, stream>>>(IDX, P, Q, d1b1, d1w2, ENC);
  decode_sqxb_kernel<<<BNn*Hd/256, 256, 0, stream>>>(ENC, d1b2, X, SQ, XB);

  // dynamic layer 2
  gemm_pq_kernel<64><<<BNn/8, 128, 0, stream>>>(X, WPQ2, P, Q);
  knn_kernel<<<Bg*32, 256, 0, stream>>>(XB, SQ, CAND);
  rerank_kernel<<<BNn/4, 256, 0, stream>>>(X, CAND, IDX);
  init_enc_kernel<<<BNn*Hd/256, 256, 0, stream>>>(ENC);
  emsg_kernel<<<En/256, 256, 0, stream>>>(IDX, P, Q, d2b1, d2w2, ENC);
  decode_kernel<<<BNn*Hd/256, 256, 0, stream>>>(ENC, d2b2, H2);

  final_kernel<<<8192, 64, 0, stream>>>(H2, linw, linb, out);
}

// Round 15
// 1244.805 us; speedup vs baseline: 1.4548x; 1.4548x over previous
//
#include <hip/hip_runtime.h>
#include <math.h>

#define Bg 32
#define Ng 2048
#define Kn 20
#define BNn (Bg*Ng)
#define En (BNn*Kn)
#define Hd 64
#define Cd 40

// knn-mfma params
#define KK 24            // approx top-K kept per j-quarter (96 cands/row)

typedef __attribute__((ext_vector_type(8))) short bf16x8;
typedef __attribute__((ext_vector_type(4))) float f32x4;

__device__ __forceinline__ unsigned enc_f32(float f){
  unsigned u = __float_as_uint(f);
  return ((int)u < 0) ? ~u : (u | 0x80000000u);
}

__device__ __forceinline__ unsigned short bf16rne(float f){
  unsigned u = __float_as_uint(f);
  return (unsigned short)((u + 0x7FFFu + ((u >> 16) & 1u)) >> 16);
}

// ---------- weight prep
__global__ void prep_w_kernel(const float* __restrict__ w1c, const float* __restrict__ w1d1,
                              const float* __restrict__ w1d2,
                              float* __restrict__ wpq0, float* __restrict__ wpq1,
                              float* __restrict__ wpq2){
  int t = blockIdx.x*256 + threadIdx.x;
  if (t < 3*128){
    int d = t >> 7, l = t & 127;
    wpq0[t] = (l < 64) ? (w1c[d*64 + l] - w1c[(d+3)*64 + l]) : w1c[(d+3)*64 + (l-64)];
  }
  if (t < 64*128){
    int d = t >> 7, l = t & 127;
    wpq1[t] = (l < 64) ? (w1d1[d*64 + l] - w1d1[(d+64)*64 + l]) : w1d1[(d+64)*64 + (l-64)];
    wpq2[t] = (l < 64) ? (w1d2[d*64 + l] - w1d2[(d+64)*64 + l]) : w1d2[(d+64)*64 + (l-64)];
  }
}

__global__ void zero_kernel(int* __restrict__ p){
  p[blockIdx.x*256 + threadIdx.x] = 0;
}

__global__ void init_enc_kernel(unsigned int* __restrict__ enc){
  enc[blockIdx.x*256 + threadIdx.x] = 0x007FFFFFu;   // enc(-inf)
}

// ---------- X[BN,D] @ wpq[D,128] -> P,Q
template<int D>
__global__ __launch_bounds__(128) void gemm_pq_kernel(const float* __restrict__ x,
                               const float* __restrict__ w,
                               float* __restrict__ P, float* __restrict__ Q){
  __shared__ float xs[8*D];
  int l = threadIdx.x;
  int node0 = blockIdx.x*8;
  float wc[D];
  #pragma unroll
  for (int d=0; d<D; d++) wc[d] = w[d*128 + l];
  for (int i=l; i < 8*D; i += 128) xs[i] = x[(size_t)node0*D + i];
  __syncthreads();
  #pragma unroll
  for (int n=0; n<8; n++){
    float s = 0.f;
    #pragma unroll
    for (int d=0; d<D; d++) s = fmaf(xs[n*D+d], wc[d], s);
    int node = node0 + n;
    if (l < 64) P[(size_t)node*64 + l] = s;
    else        Q[(size_t)node*64 + (l-64)] = s;
  }
}

// ---------- sq norms + bf16 copy of X (first static layer input path)
__global__ __launch_bounds__(256) void sqxb_kernel(const float* __restrict__ x,
        float* __restrict__ sq, unsigned short* __restrict__ xb){
  int t = blockIdx.x*256 + threadIdx.x;
  int node = t >> 6, l = t & 63;
  float v = x[t];
  xb[t] = bf16rne(v);
  float s = v*v;
  #pragma unroll
  for (int o=32; o; o>>=1) s += __shfl_xor(s, o, 64);
  if (l == 0) sq[node] = s;
}

// ---------- fused decode(+b2,+ELU) -> X, bf16 XB, SQ
__global__ __launch_bounds__(256) void decode_sqxb_kernel(const unsigned int* __restrict__ enc,
        const float* __restrict__ b2, float* __restrict__ x,
        float* __restrict__ sq, unsigned short* __restrict__ xb){
  int t = blockIdx.x*256 + threadIdx.x;
  int node = t >> 6, l = t & 63;
  unsigned int e = enc[t];
  unsigned int bits = (e & 0x80000000u) ? (e ^ 0x80000000u) : ~e;
  float f = __uint_as_float(bits);
  if (isfinite(f)) f += b2[l]; else f = 0.f;
  f = f > 0.f ? f : expm1f(f);
  x[t] = f;
  xb[t] = bf16rne(f);
  float s = f*f;
  #pragma unroll
  for (int o=32; o; o>>=1) s += __shfl_xor(s, o, 64);
  if (l == 0) sq[node] = s;
}

// ---------- CSR build
__global__ void count_kernel(const int* __restrict__ ei, int* __restrict__ deg){
  int e = blockIdx.x*256 + threadIdx.x;
  atomicAdd(&deg[ei[En + e]], 1);
}

__global__ __launch_bounds__(1024) void scan_kernel(const int* __restrict__ deg,
        int* __restrict__ rowptr, int* __restrict__ cursor){
  __shared__ int ps[1024];
  int t = threadIdx.x;
  int base = t*64;
  int s = 0;
  for (int k=0;k<64;k++) s += deg[base+k];
  ps[t] = s; __syncthreads();
  for (int off=1; off<1024; off<<=1){
    int v = (t>=off) ? ps[t-off] : 0;
    __syncthreads();
    ps[t] += v;
    __syncthreads();
  }
  int run = (t>0) ? ps[t-1] : 0;
  for (int k=0;k<64;k++){
    rowptr[base+k] = run; cursor[base+k] = run;
    run += deg[base+k];
  }
  if (t==1023) rowptr[BNn] = run;
}

__global__ void scatter_kernel(const int* __restrict__ ei, int* __restrict__ cursor,
                               int* __restrict__ csrc, int* __restrict__ enid){
  int e = blockIdx.x*256 + threadIdx.x;
  int s = ei[e], d = ei[En + e];
  int pos = atomicAdd(&cursor[d], 1);
  csrc[pos] = s;
  enid[pos] = d;
}

// swizzled LDS address: row-major [*][stride bytes], byte ^= (row&7)<<4
#define SWZ16(base, row, stridep2, byteoff) \
  ((unsigned short*)((char*)(base) + ((((row) << (stridep2)) + (byteoff)) ^ (((row) & 7) << 4))))

// ---------- static EdgeConv v2: split-bf16 MFMA GEMM + Ct-LDS run-max epilogue
__global__ __launch_bounds__(256,3) void econv_gemm_kernel(
    const int* __restrict__ csrc, const int* __restrict__ enid,
    const float* __restrict__ P, const float* __restrict__ Q,
    const float* __restrict__ b1, const float* __restrict__ w2,
    unsigned int* __restrict__ enc){
  __shared__ __align__(16) char smem[49152];
  unsigned short* Ah = (unsigned short*)smem;            // [128][64] bf16 swz, 16384
  unsigned short* Al = (unsigned short*)(smem + 16384);  // 16384
  unsigned short* Wh = (unsigned short*)(smem + 32768);  // [64 n][64 k] bf16 swz, 8192
  unsigned short* Wl = (unsigned short*)(smem + 40960);  // 8192
  float* Ct = (float*)smem;                              // [64 ch][128 row] f32 overlay
  __shared__ int eids[256];
  int tid = threadIdx.x;
  int lane = tid & 63, w = tid >> 6;
  int e0 = ((blockIdx.x & 7)*640 + (blockIdx.x >> 3))*256;   // XCD-chunked (5120 wg)

  eids[tid] = enid[e0 + tid];
  // ---- stage W2 hi/lo transposed [n][k]
  #pragma unroll
  for (int z = 0; z < 16; z++){
    int idx = z*256 + tid;
    int k = idx >> 6, n = idx & 63;
    float f = w2[idx];
    unsigned short h = bf16rne(f);
    float fh = __uint_as_float((unsigned)h << 16);
    unsigned short l = bf16rne(f - fh);
    *SWZ16(Wh, n, 7, k*2) = h;
    *SWZ16(Wl, n, 7, k*2) = l;
  }

  #pragma unroll 1
  for (int hh = 0; hh < 2; hh++){
    int eh0 = e0 + hh*128;
    __syncthreads();          // prev-half Ct reads done; eids/W visible (hh=0)
    // ---- stage A = relu(P[i]+Q[j]+b1) -> bf16 hi/lo
    {
      int el = tid >> 1, kh2 = (tid & 1) * 32;
      int e = eh0 + el;
      int i = eids[hh*128 + el];
      int j = csrc[e];
      const float* Pr = P + (size_t)i*Hd + kh2;
      const float* Qr = Q + (size_t)j*Hd + kh2;
      const float* Br = b1 + kh2;
      #pragma unroll
      for (int m = 0; m < 4; m++){
        float4 pa = ((const float4*)Pr)[2*m], pb = ((const float4*)Pr)[2*m+1];
        float4 qa = ((const float4*)Qr)[2*m], qb = ((const float4*)Qr)[2*m+1];
        float4 ba = ((const float4*)Br)[2*m], bbv = ((const float4*)Br)[2*m+1];
        float a[8];
        a[0]=fmaxf(pa.x+qa.x+ba.x,0.f);  a[1]=fmaxf(pa.y+qa.y+ba.y,0.f);
        a[2]=fmaxf(pa.z+qa.z+ba.z,0.f);  a[3]=fmaxf(pa.w+qa.w+ba.w,0.f);
        a[4]=fmaxf(pb.x+qb.x+bbv.x,0.f); a[5]=fmaxf(pb.y+qb.y+bbv.y,0.f);
        a[6]=fmaxf(pb.z+qb.z+bbv.z,0.f); a[7]=fmaxf(pb.w+qb.w+bbv.w,0.f);
        unsigned hw[4], lw[4];
        #pragma unroll
        for (int t=0;t<4;t++){
          unsigned short h0 = bf16rne(a[2*t]);
          unsigned short h1 = bf16rne(a[2*t+1]);
          float f0 = __uint_as_float((unsigned)h0 << 16);
          float f1 = __uint_as_float((unsigned)h1 << 16);
          unsigned short l0 = bf16rne(a[2*t] - f0);
          unsigned short l1 = bf16rne(a[2*t+1] - f1);
          hw[t] = (unsigned)h0 | ((unsigned)h1 << 16);
          lw[t] = (unsigned)l0 | ((unsigned)l1 << 16);
        }
        uint4 hv = {hw[0], hw[1], hw[2], hw[3]};
        uint4 lv = {lw[0], lw[1], lw[2], lw[3]};
        *(uint4*)SWZ16(Ah, el, 7, (kh2 + 8*m)*2) = hv;
        *(uint4*)SWZ16(Al, el, 7, (kh2 + 8*m)*2) = lv;
      }
    }
    __syncthreads();
    // ---- MFMA: wave w computes rows [w*32, w*32+32) x 64 cols
    bf16x8 Af[2][2], Lf[2][2];
    #pragma unroll
    for (int mt=0; mt<2; mt++)
      #pragma unroll
      for (int s=0; s<2; s++){
        int row = w*32 + mt*16 + (lane & 15);
        Af[mt][s] = *(const bf16x8*)SWZ16(Ah, row, 7, (s*32 + (lane>>4)*8)*2);
        Lf[mt][s] = *(const bf16x8*)SWZ16(Al, row, 7, (s*32 + (lane>>4)*8)*2);
      }
    f32x4 acc[2][4];
    #pragma unroll
    for (int mt=0; mt<2; mt++)
      #pragma unroll
      for (int nt=0; nt<4; nt++)
        acc[mt][nt] = (f32x4){0.f,0.f,0.f,0.f};
    #pragma unroll
    for (int nt=0; nt<4; nt++){
      int n = nt*16 + (lane & 15);
      bf16x8 Bh0 = *(const bf16x8*)SWZ16(Wh, n, 7, ((lane>>4)*8)*2);
      bf16x8 Bh1 = *(const bf16x8*)SWZ16(Wh, n, 7, (32 + (lane>>4)*8)*2);
      bf16x8 Bl0 = *(const bf16x8*)SWZ16(Wl, n, 7, ((lane>>4)*8)*2);
      bf16x8 Bl1 = *(const bf16x8*)SWZ16(Wl, n, 7, (32 + (lane>>4)*8)*2);
      #pragma unroll
      for (int mt=0; mt<2; mt++){
        f32x4 a_ = acc[mt][nt];
        a_ = __builtin_amdgcn_mfma_f32_16x16x32_bf16(Af[mt][0], Bh0, a_, 0, 0, 0);
        a_ = __builtin_amdgcn_mfma_f32_16x16x32_bf16(Af[mt][1], Bh1, a_, 0, 0, 0);
        a_ = __builtin_amdgcn_mfma_f32_16x16x32_bf16(Af[mt][0], Bl0, a_, 0, 0, 0);
        a_ = __builtin_amdgcn_mfma_f32_16x16x32_bf16(Af[mt][1], Bl1, a_, 0, 0, 0);
        a_ = __builtin_amdgcn_mfma_f32_16x16x32_bf16(Lf[mt][0], Bh0, a_, 0, 0, 0);
        a_ = __builtin_amdgcn_mfma_f32_16x16x32_bf16(Lf[mt][1], Bh1, a_, 0, 0, 0);
        acc[mt][nt] = a_;
      }
    }
    __syncthreads();          // Ah/Al dead -> Ct overlay
    // ---- write C^T to LDS (swizzled)
    #pragma unroll
    for (int mt=0; mt<2; mt++){
      int rb = w*32 + mt*16 + (lane>>4)*4;
      #pragma unroll
      for (int nt=0; nt<4; nt++){
        int ch = nt*16 + (lane & 15);
        #pragma unroll
        for (int v=0; v<4; v++)
          Ct[ch*128 + ((rb+v) ^ (ch & 31))] = acc[mt][nt][v];
      }
    }
    __syncthreads();
    // ---- epilogue: per (ch, 32-row part) run-max over eids -> atomicMax(enc)
    {
      int ch = tid & 63, part = tid >> 6;
      int rbase = part*32;
      int cur = eids[hh*128 + rbase];
      float vmax = -INFINITY;
      #pragma unroll 1
      for (int r = 0; r < 32; r++){
        int row = rbase + r;
        int id = eids[hh*128 + row];
        float v = Ct[ch*128 + (row ^ (ch & 31))];
        if (id != cur){
          atomicMax(&enc[(size_t)cur*Hd + ch], enc_f32(vmax));
          vmax = -INFINITY; cur = id;
        }
        vmax = fmaxf(vmax, v);
      }
      atomicMax(&enc[(size_t)cur*Hd + ch], enc_f32(vmax));
    }
  }
}

// ---------- kNN: bf16-MFMA approx distances + per-quarter top-24 (u32 keys)
// v12 (R13, kept): registerized pending + merge-flush + bitonic warm-start.
#define KNN_MFLUSH(bm) do { \
  unsigned Lm[32]; \
  _Pragma("unroll") \
  for (int t=0;t<KK;t++) Lm[t] = kb[t]; \
  _Pragma("unroll") \
  for (int k2=2;k2<=8;k2<<=1) \
    _Pragma("unroll") \
    for (int j2=k2>>1;j2>0;j2>>=1) \
      _Pragma("unroll") \
      for (int i2=0;i2<8;i2++){ \
        int ixj=i2^j2; \
        if (ixj>i2){ \
          unsigned a=bm[i2], c=bm[ixj]; \
          unsigned lo = a<c?a:c, hi = a<c?c:a; \
          bool up = ((i2 & k2)==0); \
          bm[i2] = up?lo:hi; bm[ixj] = up?hi:lo; \
        } \
      } \
  _Pragma("unroll") \
  for (int t=0;t<8;t++) Lm[24+t] = bm[7-t]; \
  _Pragma("unroll") \
  for (int j2=16;j2>0;j2>>=1) \
    _Pragma("unroll") \
    for (int i2=0;i2<32;i2++){ \
      int ixj=i2^j2; \
      if (ixj>i2){ \
        unsigned a=Lm[i2], c=Lm[ixj]; \
        Lm[i2] = a<c?a:c; Lm[ixj] = a<c?c:a; \
      } \
    } \
  _Pragma("unroll") \
  for (int t=0;t<KK;t++) kb[t] = Lm[t]; \
  kbLast = kb[KK-1]; \
} while(0)

__global__ __launch_bounds__(256,4) void knn_kernel(
    const unsigned short* __restrict__ xb, const float* __restrict__ sq,
    unsigned short* __restrict__ cand){
  __shared__ __align__(16) unsigned short xjb[128*64];    // 16384 B (swizzled)
  __shared__ __align__(16) unsigned short Dt[64*128];     // 16384 B (u16 keys, swizzled)
  __shared__ float sqs[128];                              // 512 B  => 33280 B total

  int tid = threadIdx.x;
  int lane = tid & 63, w = tid >> 6;
  int bid = ((blockIdx.x & 7) << 7) | (blockIdx.x >> 3);  // XCD-chunked (1024 wg)
  int g  = bid >> 5;
  int r0 = (bid & 31) * 64;
  const unsigned short* xbg = xb + (size_t)g*Ng*Hd;
  const float* sg = sq + (size_t)g*Ng;

  int q = w;
  int prow = lane;
  int rw = w*16;

  // ---- A fragments direct from global (rows are L2-hot; no LDS staging)
  bf16x8 A0, A1;
  {
    int arow = r0 + rw + (lane & 15);
    A0 = *(const bf16x8*)(xbg + (size_t)arow*Hd +      (lane>>4)*8);
    A1 = *(const bf16x8*)(xbg + (size_t)arow*Hd + 32 + (lane>>4)*8);
  }
  // ---- stage xjb (swizzled) + sqs
  {
    int jr = tid >> 1, half = tid & 1;
    int jloc = (jr >> 5)*512 + (jr & 31);
    const uint4* src = (const uint4*)(xbg + (size_t)jloc*Hd + half*32);
    uint4 a = src[0], b = src[1], c2 = src[2], d2 = src[3];
    *(uint4*)SWZ16(xjb, jr, 7, half*64 +  0) = a;
    *(uint4*)SWZ16(xjb, jr, 7, half*64 + 16) = b;
    *(uint4*)SWZ16(xjb, jr, 7, half*64 + 32) = c2;
    *(uint4*)SWZ16(xjb, jr, 7, half*64 + 48) = d2;
    if (tid < 128) sqs[tid] = sg[(tid>>5)*512 + (tid&31)];
  }

  unsigned kb[KK];
  #pragma unroll
  for (int t=0;t<KK;t++) kb[t] = 0xFFFFFFFFu;
  unsigned kbLast = 0xFFFFFFFFu;

  __syncthreads();

  #pragma unroll 1
  for (int it = 0; it < 16; it++){
    uint4 pf0, pf1, pf2, pf3; float psq = 0.f;
    int itn = it + 1;
    int jr = tid >> 1, half = tid & 1;
    if (itn < 16){
      int jloc = (jr >> 5)*512 + itn*32 + (jr & 31);
      const uint4* src = (const uint4*)(xbg + (size_t)jloc*Hd + half*32);
      pf0 = src[0]; pf1 = src[1]; pf2 = src[2]; pf3 = src[3];
      if (tid < 128) psq = sg[(tid>>5)*512 + itn*32 + (tid&31)];
    }
    #pragma unroll
    for (int jb = 0; jb < 8; jb++){
      int brow = jb*16 + (lane & 15);
      bf16x8 B0 = *(const bf16x8*)SWZ16(xjb, brow, 7,      (lane>>4)*16);
      bf16x8 B1 = *(const bf16x8*)SWZ16(xjb, brow, 7, 64 + (lane>>4)*16);
      f32x4 acc = {0.f, 0.f, 0.f, 0.f};
      acc = __builtin_amdgcn_mfma_f32_16x16x32_bf16(A0, B0, acc, 0, 0, 0);
      acc = __builtin_amdgcn_mfma_f32_16x16x32_bf16(A1, B1, acc, 0, 0, 0);
      int col = jb*16 + (lane & 15);
      float sqv = sqs[col];
      int rbase = rw + (lane>>4)*4;
      #pragma unroll
      for (int v=0; v<4; v++){
        // sortable u16 encode of f = -2*dot + sqj  (top 16 bits of sign-flipped f32)
        float f = fmaf(acc[v], -2.f, sqv);
        unsigned u = __float_as_uint(f);
        unsigned t2 = ((unsigned)((int)u >> 31)) | 0x8000u;
        *SWZ16(Dt, rbase + v, 8, col*2) = (unsigned short)((u >> 16) ^ t2);
      }
    }
    __syncthreads();
    if (it == 0){
      // warm start: sort this lane's 32 keys (bitonic, registers), kb = smallest 24
      unsigned key[32];
      const char* dbase = (const char*)Dt + (prow << 8);
      unsigned m = (prow & 7) << 4;
      #pragma unroll
      for (int r4=0; r4<4; r4++){
        uint4 dv = *(const uint4*)(dbase + ((unsigned)(q*64 + r4*16) ^ m));
        int cb = q*512 + r4*8;
        key[r4*8+0] = (dv.x << 16) + (unsigned)(cb + 0);
        key[r4*8+1] = (dv.x & 0xFFFF0000u) | (unsigned)(cb + 1);
        key[r4*8+2] = (dv.y << 16) + (unsigned)(cb + 2);
        key[r4*8+3] = (dv.y & 0xFFFF0000u) | (unsigned)(cb + 3);
        key[r4*8+4] = (dv.z << 16) + (unsigned)(cb + 4);
        key[r4*8+5] = (dv.z & 0xFFFF0000u) | (unsigned)(cb + 5);
        key[r4*8+6] = (dv.w << 16) + (unsigned)(cb + 6);
        key[r4*8+7] = (dv.w & 0xFFFF0000u) | (unsigned)(cb + 7);
      }
      #pragma unroll
      for (int k2 = 2; k2 <= 32; k2 <<= 1){
        #pragma unroll
        for (int j2 = k2>>1; j2 > 0; j2 >>= 1){
          #pragma unroll
          for (int i2 = 0; i2 < 32; i2++){
            int ixj = i2 ^ j2;
            if (ixj > i2){
              unsigned a = key[i2], b = key[ixj];
              unsigned lo = a < b ? a : b;
              unsigned hi = a < b ? b : a;
              bool up = ((i2 & k2) == 0);
              key[i2]  = up ? lo : hi;
              key[ixj] = up ? hi : lo;
            }
          }
        }
      }
      #pragma unroll
      for (int t=0;t<KK;t++) kb[t] = key[t];
      kbLast = kb[KK-1];
    } else {
      int jbase0 = q*512 + it*32;
      const char* dbase = (const char*)Dt + (prow << 8);
      unsigned m = (prow & 7) << 4;
      #pragma unroll
      for (int r4=0; r4<4; r4++){
        uint4 dv = *(const uint4*)(dbase + ((unsigned)(q*64 + r4*16) ^ m));
        int cb = jbase0 + r4*8;
        unsigned k0 = (dv.x << 16) + (unsigned)(cb + 0);
        unsigned k1 = (dv.x & 0xFFFF0000u) | (unsigned)(cb + 1);
        unsigned k2v = (dv.y << 16) + (unsigned)(cb + 2);
        unsigned k3 = (dv.y & 0xFFFF0000u) | (unsigned)(cb + 3);
        unsigned k4 = (dv.z << 16) + (unsigned)(cb + 4);
        unsigned k5 = (dv.z & 0xFFFF0000u) | (unsigned)(cb + 5);
        unsigned k6 = (dv.w << 16) + (unsigned)(cb + 6);
        unsigned k7 = (dv.w & 0xFFFF0000u) | (unsigned)(cb + 7);
        unsigned bm[8];
        bm[0] = (k0 < kbLast) ? k0 : 0xFFFFFFFFu;
        bm[1] = (k1 < kbLast) ? k1 : 0xFFFFFFFFu;
        bm[2] = (k2v < kbLast) ? k2v : 0xFFFFFFFFu;
        bm[3] = (k3 < kbLast) ? k3 : 0xFFFFFFFFu;
        bm[4] = (k4 < kbLast) ? k4 : 0xFFFFFFFFu;
        bm[5] = (k5 < kbLast) ? k5 : 0xFFFFFFFFu;
        bm[6] = (k6 < kbLast) ? k6 : 0xFFFFFFFFu;
        bm[7] = (k7 < kbLast) ? k7 : 0xFFFFFFFFu;
        unsigned mn01 = bm[0] < bm[1] ? bm[0] : bm[1];
        unsigned mn23 = bm[2] < bm[3] ? bm[2] : bm[3];
        unsigned mn45 = bm[4] < bm[5] ? bm[4] : bm[5];
        unsigned mn67 = bm[6] < bm[7] ? bm[6] : bm[7];
        unsigned mn03 = mn01 < mn23 ? mn01 : mn23;
        unsigned mn47 = mn45 < mn67 ? mn45 : mn67;
        unsigned mn = mn03 < mn47 ? mn03 : mn47;
        if (__any(mn != 0xFFFFFFFFu)) KNN_MFLUSH(bm);
      }
    }
    if (itn < 16){
      *(uint4*)SWZ16(xjb, jr, 7, half*64 +  0) = pf0;
      *(uint4*)SWZ16(xjb, jr, 7, half*64 + 16) = pf1;
      *(uint4*)SWZ16(xjb, jr, 7, half*64 + 32) = pf2;
      *(uint4*)SWZ16(xjb, jr, 7, half*64 + 48) = pf3;
      if (tid < 128) sqs[tid] = psq;
    }
    __syncthreads();
  }
  size_t base = (size_t)(g*Ng + r0 + prow)*96 + q*24;
  #pragma unroll
  for (int t=0;t<KK;t++)
    cand[base + t] = (unsigned short)(kb[t] & 2047u);
}

// ---------- exact rerank v5 (R13, restored): XCD-chunked + all-24-loads-in-flight
//   [R14 lesson: __launch_bounds__(256,4) split the unified reg file (VGPR=64 +
//    scratch spill, 2.1GB traffic). NEVER set min-waves >= 3 on reg-heavy kernels.]
__global__ __launch_bounds__(256,2) void rerank_kernel(const float* __restrict__ x,
        const unsigned short* __restrict__ cand, int* __restrict__ idx){
  __shared__ __align__(16) unsigned long long ks[4][96];
  int tid = threadIdx.x;
  int lane = tid & 63, w = tid >> 6;
  int bid = ((blockIdx.x & 7) << 11) | (blockIdx.x >> 3);   // XCD-chunked (16384 wg)
  int row = bid*4 + w;
  int g = row >> 11;
  const float* xg = x + (size_t)g*Ng*Hd;
  int chunk = lane & 3;        // 16B chunk within a row
  int cg = lane >> 2;          // candidate group 0..15
  const float* xr = x + (size_t)row*Hd;
  float4 xc[4];
  #pragma unroll
  for (int it2=0; it2<4; it2++) xc[it2] = *(const float4*)(xr + 16*it2 + 4*chunk);

  int js[6];
  #pragma unroll
  for (int p=0; p<6; p++) js[p] = cand[(size_t)row*96 + p*16 + cg];

  // phase 1: issue all 24 gathers (static indices -> registers, deep MLP)
  float4 bb[6][4];
  #pragma unroll
  for (int p=0; p<6; p++){
    const float* xj = xg + (size_t)js[p]*Hd;
    #pragma unroll
    for (int it2=0; it2<4; it2++) bb[p][it2] = *(const float4*)(xj + 16*it2 + 4*chunk);
  }
  // phase 2: reduce
  #pragma unroll
  for (int p=0; p<6; p++){
    float dot = 0.f, sqj = 0.f;
    #pragma unroll
    for (int it2=0; it2<4; it2++){
      float4 b = bb[p][it2];
      float4 a = xc[it2];
      dot = fmaf(a.x, b.x, dot); dot = fmaf(a.y, b.y, dot);
      dot = fmaf(a.z, b.z, dot); dot = fmaf(a.w, b.w, dot);
      sqj = fmaf(b.x, b.x, sqj); sqj = fmaf(b.y, b.y, sqj);
      sqj = fmaf(b.z, b.z, sqj); sqj = fmaf(b.w, b.w, sqj);
    }
    dot += __shfl_xor(dot, 1, 64); dot += __shfl_xor(dot, 2, 64);
    sqj += __shfl_xor(sqj, 1, 64); sqj += __shfl_xor(sqj, 2, 64);
    if (chunk == 0){
      float dist = fmaf(dot, -2.f, sqj);   // row-constant +sq_i dropped (order-invariant)
      ks[w][p*16 + cg] = ((unsigned long long)enc_f32(dist) << 32) | (unsigned)js[p];
    }
  }
  __syncthreads();
  unsigned long long k0 = ks[w][lane];
  unsigned long long k1 = (lane < 32) ? ks[w][64 + lane] : ~0ULL;
  int r0 = 0, r1 = 0;
  #pragma unroll
  for (int c=0;c<96;c+=2){
    unsigned long long a = ks[w][c], b = ks[w][c+1];
    r0 += (a < k0) + (b < k0);
    r1 += (a < k1) + (b < k1);
  }
  if (r0 < Kn) idx[(size_t)row*Kn + r0] = g*Ng + (int)(k0 & 2047ULL);
  if (lane < 32 && r1 < Kn) idx[(size_t)row*Kn + r1] = g*Ng + (int)(k1 & 2047ULL);
}

// ---------- dynamic EdgeConv stage 2 v2: split-bf16 MFMA GEMM (bf16x3)
__global__ __launch_bounds__(256,3) void emsg_kernel(
    const int* __restrict__ srcl,
    const float* __restrict__ P, const float* __restrict__ Q,
    const float* __restrict__ b1, const float* __restrict__ w2,
    unsigned int* __restrict__ enc){
  __shared__ __align__(16) char smem[49152];
  unsigned short* Ah = (unsigned short*)smem;            // [128][64] bf16 swz, 16384
  unsigned short* Al = (unsigned short*)(smem + 16384);  // 16384
  unsigned short* Wh = (unsigned short*)(smem + 32768);  // [64 n][64 k] bf16 swz, 8192
  unsigned short* Wl = (unsigned short*)(smem + 40960);  // 8192
  float* p0 = (float*)smem;                              // [64][33] f32 overlay on Ah/Al
  float* p1 = (float*)(smem + 8448);
  int tid = threadIdx.x;
  int lane = tid & 63, w = tid >> 6;
  int e0 = ((blockIdx.x & 7)*640 + (blockIdx.x >> 3))*256;   // XCD-chunked (5120 wg)

  // ---- stage W2 hi/lo transposed [n][k] (once; n = tid&63, k = z*4 + tid>>6)
  #pragma unroll
  for (int z = 0; z < 16; z++){
    int idx = z*256 + tid;
    int k = idx >> 6, n = idx & 63;
    float f = w2[idx];
    unsigned short h = bf16rne(f);
    float fh = __uint_as_float((unsigned)h << 16);
    unsigned short l = bf16rne(f - fh);
    *SWZ16(Wh, n, 7, k*2) = h;
    *SWZ16(Wl, n, 7, k*2) = l;
  }

  #pragma unroll 1
  for (int hh = 0; hh < 2; hh++){
    int eh0 = e0 + hh*128;
    __syncthreads();          // prev-half p-reads done; W stage visible
    // ---- stage A = relu(P[i]+Q[j]+b1) -> bf16 hi/lo (thread: edge tid>>1, k-half (tid&1)*32)
    {
      int el = tid >> 1, kh = (tid & 1) * 32;
      int e = eh0 + el;
      int i = e / Kn;
      int j = srcl[e];
      const float* Pr = P + (size_t)i*Hd + kh;
      const float* Qr = Q + (size_t)j*Hd + kh;
      const float* Br = b1 + kh;
      #pragma unroll
      for (int m = 0; m < 4; m++){
        float4 pa = ((const float4*)Pr)[2*m], pb = ((const float4*)Pr)[2*m+1];
        float4 qa = ((const float4*)Qr)[2*m], qb = ((const float4*)Qr)[2*m+1];
        float4 ba = ((const float4*)Br)[2*m], bbv = ((const float4*)Br)[2*m+1];
        float a[8];
        a[0]=fmaxf(pa.x+qa.x+ba.x,0.f);  a[1]=fmaxf(pa.y+qa.y+ba.y,0.f);
        a[2]=fmaxf(pa.z+qa.z+ba.z,0.f);  a[3]=fmaxf(pa.w+qa.w+ba.w,0.f);
        a[4]=fmaxf(pb.x+qb.x+bbv.x,0.f); a[5]=fmaxf(pb.y+qb.y+bbv.y,0.f);
        a[6]=fmaxf(pb.z+qb.z+bbv.z,0.f); a[7]=fmaxf(pb.w+qb.w+bbv.w,0.f);
        unsigned hw[4], lw[4];
        #pragma unroll
        for (int t=0;t<4;t++){
          unsigned short h0 = bf16rne(a[2*t]);
          unsigned short h1 = bf16rne(a[2*t+1]);
          float f0 = __uint_as_float((unsigned)h0 << 16);
          float f1 = __uint_as_float((unsigned)h1 << 16);
          unsigned short l0 = bf16rne(a[2*t] - f0);
          unsigned short l1 = bf16rne(a[2*t+1] - f1);
          hw[t] = (unsigned)h0 | ((unsigned)h1 << 16);
          lw[t] = (unsigned)l0 | ((unsigned)l1 << 16);
        }
        uint4 hv = {hw[0], hw[1], hw[2], hw[3]};
        uint4 lv = {lw[0], lw[1], lw[2], lw[3]};
        *(uint4*)SWZ16(Ah, el, 7, (kh + 8*m)*2) = hv;
        *(uint4*)SWZ16(Al, el, 7, (kh + 8*m)*2) = lv;
      }
    }
    __syncthreads();
    // ---- MFMA: wave w computes rows [w*32, w*32+32) x 64 cols
    bf16x8 Af[2][2], Lf[2][2];
    #pragma unroll
    for (int mt=0; mt<2; mt++)
      #pragma unroll
      for (int s=0; s<2; s++){
        int row = w*32 + mt*16 + (lane & 15);
        Af[mt][s] = *(const bf16x8*)SWZ16(Ah, row, 7, (s*32 + (lane>>4)*8)*2);
        Lf[mt][s] = *(const bf16x8*)SWZ16(Al, row, 7, (s*32 + (lane>>4)*8)*2);
      }
    f32x4 acc[2][4];
    #pragma unroll
    for (int mt=0; mt<2; mt++)
      #pragma unroll
      for (int nt=0; nt<4; nt++)
        acc[mt][nt] = (f32x4){0.f,0.f,0.f,0.f};
    #pragma unroll
    for (int nt=0; nt<4; nt++){
      int n = nt*16 + (lane & 15);
      bf16x8 Bh0 = *(const bf16x8*)SWZ16(Wh, n, 7, ((lane>>4)*8)*2);
      bf16x8 Bh1 = *(const bf16x8*)SWZ16(Wh, n, 7, (32 + (lane>>4)*8)*2);
      bf16x8 Bl0 = *(const bf16x8*)SWZ16(Wl, n, 7, ((lane>>4)*8)*2);
      bf16x8 Bl1 = *(const bf16x8*)SWZ16(Wl, n, 7, (32 + (lane>>4)*8)*2);
      #pragma unroll
      for (int mt=0; mt<2; mt++){
        f32x4 a_ = acc[mt][nt];
        a_ = __builtin_amdgcn_mfma_f32_16x16x32_bf16(Af[mt][0], Bh0, a_, 0, 0, 0);
        a_ = __builtin_amdgcn_mfma_f32_16x16x32_bf16(Af[mt][1], Bh1, a_, 0, 0, 0);
        a_ = __builtin_amdgcn_mfma_f32_16x16x32_bf16(Af[mt][0], Bl0, a_, 0, 0, 0);
        a_ = __builtin_amdgcn_mfma_f32_16x16x32_bf16(Af[mt][1], Bl1, a_, 0, 0, 0);
        a_ = __builtin_amdgcn_mfma_f32_16x16x32_bf16(Lf[mt][0], Bh0, a_, 0, 0, 0);
        a_ = __builtin_amdgcn_mfma_f32_16x16x32_bf16(Lf[mt][1], Bh1, a_, 0, 0, 0);
        acc[mt][nt] = a_;
      }
    }
    __syncthreads();          // Ah/Al dead -> p0/p1 overlay
    // ---- p-writes: 4-row chunks, <=2 nodes per chunk (4 < Kn)
    #pragma unroll
    for (int mt=0; mt<2; mt++){
      int rb = w*32 + mt*16 + (lane>>4)*4;
      int rbg = eh0 + rb;
      int nd0 = rbg / Kn;
      int split = (nd0+1)*Kn - rbg; if (split > 4) split = 4;
      int cm = rb >> 2;
      #pragma unroll
      for (int nt=0; nt<4; nt++){
        int ch = nt*16 + (lane & 15);
        float s0v = -INFINITY, s1v = -INFINITY;
        #pragma unroll
        for (int v=0; v<4; v++){
          float val = acc[mt][nt][v];
          if (v < split) s0v = fmaxf(s0v, val); else s1v = fmaxf(s1v, val);
        }
        p0[ch*33 + cm] = s0v;
        p1[ch*33 + cm] = s1v;
      }
    }
    __syncthreads();
    // ---- reduce + atomicMax
    int nfirst = eh0 / Kn;
    int ncnt = (eh0 + 127) / Kn - nfirst + 1;
    int ch = tid & 63;
    for (int ln = tid >> 6; ln < ncnt; ln += 4){
      int nd = nfirst + ln;
      int glo = nd*Kn;      if (glo < eh0)     glo = eh0;
      int ghi = nd*Kn + Kn; if (ghi > eh0+128) ghi = eh0+128;
      int mlo = (glo - eh0) >> 2, mhi = (ghi - 1 - eh0) >> 2;
      float v = -INFINITY;
      for (int mm = mlo; mm <= mhi; mm++){
        int bn = (eh0 + 4*mm) / Kn;
        if (bn == nd)     v = fmaxf(v, p0[ch*33 + mm]);
        if (bn + 1 == nd) v = fmaxf(v, p1[ch*33 + mm]);
      }
      atomicMax(&enc[(size_t)nd*Hd + ch], enc_f32(v));
    }
  }
}

// ---------- final decode (no ELU): enc -> float + b2
__global__ __launch_bounds__(256) void decode_kernel(const unsigned int* __restrict__ enc,
         const float* __restrict__ b2, float* __restrict__ x){
  int t = blockIdx.x*256 + threadIdx.x;
  unsigned int e = enc[t];
  unsigned int bits = (e & 0x80000000u) ? (e ^ 0x80000000u) : ~e;
  float f = __uint_as_float(bits);
  if (isfinite(f)) f += b2[t & 63]; else f = 0.f;
  x[t] = f;
}

__global__ __launch_bounds__(64) void final_kernel(const float* __restrict__ h,
        const float* __restrict__ w, const float* __restrict__ bias,
        float* __restrict__ out){
  __shared__ float xs[Hd];
  int c = threadIdx.x;
  float wc[Hd];
  float bc = 0.f;
  if (c < Cd){
    #pragma unroll
    for (int d=0; d<Hd; d++) wc[d] = w[d*Cd + c];
    bc = bias[c];
  }
  for (int i = blockIdx.x; i < BNn; i += gridDim.x){
    __syncthreads();
    xs[c] = h[(size_t)i*Hd + c];
    __syncthreads();
    if (c < Cd){
      float s = bc;
      #pragma unroll
      for (int d=0; d<Hd; d++) s = fmaf(xs[d], wc[d], s);
      out[(size_t)i*Cd + c] = s;
    }
  }
}

extern "C" void kernel_launch(void* const* d_in, const int* in_sizes, int n_in,
                              void* d_out, int out_size, void* d_ws, size_t ws_size,
                              hipStream_t stream){
  const float* x0   = (const float*)d_in[0];
  const int*   ei   = (const int*)d_in[1];
  const float* c1w1 = (const float*)d_in[3];
  const float* c1b1 = (const float*)d_in[4];
  const float* c1w2 = (const float*)d_in[5];
  const float* c1b2 = (const float*)d_in[6];
  const float* d1w1 = (const float*)d_in[7];
  const float* d1b1 = (const float*)d_in[8];
  const float* d1w2 = (const float*)d_in[9];
  const float* d1b2 = (const float*)d_in[10];
  const float* d2w1 = (const float*)d_in[11];
  const float* d2b1 = (const float*)d_in[12];
  const float* d2w2 = (const float*)d_in[13];
  const float* d2b2 = (const float*)d_in[14];
  const float* linw = (const float*)d_in[15];
  const float* linb = (const float*)d_in[16];
  float* out = (float*)d_out;

  char* ws = (char*)d_ws;
  size_t off = 0;
  auto alloc = [&](size_t bytes)->char*{
    char* p = ws + off; off += (bytes + 255) & ~(size_t)255; return p;
  };
  float*        X    = (float*)alloc(sizeof(float)*(size_t)BNn*Hd);
  float*        P    = (float*)alloc(sizeof(float)*(size_t)BNn*Hd);
  float*        Q    = (float*)alloc(sizeof(float)*(size_t)BNn*Hd);
  float*        H2   = (float*)alloc(sizeof(float)*(size_t)BNn*Hd);  // aliases XB, ENID
  unsigned int* ENC  = (unsigned int*)alloc(sizeof(unsigned)*(size_t)BNn*Hd); // aliases CAND
  int*          SHRD = (int*)alloc(sizeof(int)*(size_t)En);   // CSRC, later IDX
  int*          DEG  = (int*)alloc(sizeof(int)*BNn);
  int*          RPTR = (int*)alloc(sizeof(int)*(BNn+1));
  int*          CUR  = (int*)alloc(sizeof(int)*BNn);
  float*        SQ   = (float*)alloc(sizeof(float)*BNn);
  float*        WPQ0 = (float*)alloc(sizeof(float)*3*128);
  float*        WPQ1 = (float*)alloc(sizeof(float)*64*128);
  float*        WPQ2 = (float*)alloc(sizeof(float)*64*128);
  int*            CSRC = SHRD;
  int*            IDX  = SHRD;
  int*            ENID = (int*)H2;
  unsigned short* XB   = (unsigned short*)H2;
  unsigned short* CAND = (unsigned short*)ENC;
  (void)ws_size; (void)in_sizes; (void)n_in; (void)out_size;

  // static EdgeConv: CSR sort + edge-batched MFMA GEMM + run-max + fused decode
  prep_w_kernel<<<32, 256, 0, stream>>>(c1w1, d1w1, d2w1, WPQ0, WPQ1, WPQ2);
  zero_kernel<<<BNn/256, 256, 0, stream>>>(DEG);
  count_kernel<<<En/256, 256, 0, stream>>>(ei, DEG);
  gemm_pq_kernel<3><<<BNn/8, 128, 0, stream>>>(x0, WPQ0, P, Q);
  scan_kernel<<<1, 1024, 0, stream>>>(DEG, RPTR, CUR);
  scatter_kernel<<<En/256, 256, 0, stream>>>(ei, CUR, CSRC, ENID);
  init_enc_kernel<<<BNn*Hd/256, 256, 0, stream>>>(ENC);
  econv_gemm_kernel<<<En/256, 256, 0, stream>>>(CSRC, ENID, P, Q, c1b1, c1w2, ENC);
  decode_sqxb_kernel<<<BNn*Hd/256, 256, 0, stream>>>(ENC, c1b2, X, SQ, XB);

  // dynamic layer 1
  gemm_pq_kernel<64><<<BNn/8, 128, 0, stream>>>(X, WPQ1, P, Q);
  knn_kernel<<<Bg*32, 256, 0, stream>>>(XB, SQ, CAND);
  rerank_kernel<<<BNn/4, 256, 0, stream>>>(X, CAND, IDX);
  init_enc_kernel<<<BNn*Hd/256, 256, 0, stream>>>(ENC);
  emsg_kernel<<<En/256, 256, 0, stream>>>(IDX, P, Q, d1b1, d1w2, ENC);
  decode_sqxb_kernel<<<BNn*Hd/256, 256, 0, stream>>>(ENC, d1b2, X, SQ, XB);

  // dynamic layer 2
  gemm_pq_kernel<64><<<BNn/8, 128, 0, stream>>>(X, WPQ2, P, Q);
  knn_kernel<<<Bg*32, 256, 0, stream>>>(XB, SQ, CAND);
  rerank_kernel<<<BNn/4, 256, 0, stream>>>(X, CAND, IDX);
  init_enc_kernel<<<BNn*Hd/256, 256, 0, stream>>>(ENC);
  emsg_kernel<<<En/256, 256, 0, stream>>>(IDX, P, Q, d2b1, d2w2, ENC);
  decode_kernel<<<BNn*Hd/256, 256, 0, stream>>>(ENC, d2b2, H2);

  final_kernel<<<8192, 64, 0, stream>>>(H2, linw, linb, out);
}

// Round 16
// 1206.823 us; speedup vs baseline: 1.5006x; 1.0315x over previous
//
#include <hip/hip_runtime.h>
#include <math.h>

#define Bg 32
#define Ng 2048
#define Kn 20
#define BNn (Bg*Ng)
#define En (BNn*Kn)
#define Hd 64
#define Cd 40

// knn-mfma params
#define KK 24            // approx top-K kept per j-quarter (96 cands/row)

typedef __attribute__((ext_vector_type(8))) short bf16x8;
typedef __attribute__((ext_vector_type(4))) float f32x4;

__device__ __forceinline__ unsigned enc_f32(float f){
  unsigned u = __float_as_uint(f);
  return ((int)u < 0) ? ~u : (u | 0x80000000u);
}

__device__ __forceinline__ unsigned short bf16rne(float f){
  unsigned u = __float_as_uint(f);
  return (unsigned short)((u + 0x7FFFu + ((u >> 16) & 1u)) >> 16);
}

// ---------- weight prep + DEG zero (fused; grid = BNn/256 = 256 blocks)
__global__ void prep_w_kernel(const float* __restrict__ w1c, const float* __restrict__ w1d1,
                              const float* __restrict__ w1d2,
                              float* __restrict__ wpq0, float* __restrict__ wpq1,
                              float* __restrict__ wpq2, int* __restrict__ deg){
  int t = blockIdx.x*256 + threadIdx.x;
  deg[t] = 0;                       // t < BNn by grid construction
  if (t < 3*128){
    int d = t >> 7, l = t & 127;
    wpq0[t] = (l < 64) ? (w1c[d*64 + l] - w1c[(d+3)*64 + l]) : w1c[(d+3)*64 + (l-64)];
  }
  if (t < 64*128){
    int d = t >> 7, l = t & 127;
    wpq1[t] = (l < 64) ? (w1d1[d*64 + l] - w1d1[(d+64)*64 + l]) : w1d1[(d+64)*64 + (l-64)];
    wpq2[t] = (l < 64) ? (w1d2[d*64 + l] - w1d2[(d+64)*64 + l]) : w1d2[(d+64)*64 + (l-64)];
  }
}

__global__ void init_enc_kernel(unsigned int* __restrict__ enc){
  enc[blockIdx.x*256 + threadIdx.x] = 0x007FFFFFu;   // enc(-inf)
}

// ---------- X[BN,D] @ wpq[D,128] -> P,Q  (static layer, D=3)
template<int D>
__global__ __launch_bounds__(128) void gemm_pq_kernel(const float* __restrict__ x,
                               const float* __restrict__ w,
                               float* __restrict__ P, float* __restrict__ Q){
  __shared__ float xs[8*D];
  int l = threadIdx.x;
  int node0 = blockIdx.x*8;
  float wc[D];
  #pragma unroll
  for (int d=0; d<D; d++) wc[d] = w[d*128 + l];
  for (int i=l; i < 8*D; i += 128) xs[i] = x[(size_t)node0*D + i];
  __syncthreads();
  #pragma unroll
  for (int n=0; n<8; n++){
    float s = 0.f;
    #pragma unroll
    for (int d=0; d<D; d++) s = fmaf(xs[n*D+d], wc[d], s);
    int node = node0 + n;
    if (l < 64) P[(size_t)node*64 + l] = s;
    else        Q[(size_t)node*64 + (l-64)] = s;
  }
}

// ---------- fused: decode(+b2,+ELU) from ENC -> X/XB/SQ + re-arm ENC + P,Q GEMM
//   Replaces decode_sqxb_kernel + gemm_pq<64> (one launch per dynamic layer);
//   the enc re-arm (same thread, same address) also replaces init_enc #2/#3.
__global__ __launch_bounds__(128) void decode_gemm_pq_kernel(
    unsigned int* __restrict__ enc, const float* __restrict__ b2,
    const float* __restrict__ w,
    float* __restrict__ X, float* __restrict__ sq, unsigned short* __restrict__ xb,
    float* __restrict__ P, float* __restrict__ Q){
  __shared__ float xs[8*Hd];
  int l = threadIdx.x;
  int node0 = blockIdx.x*8;
  float wc[Hd];
  #pragma unroll
  for (int d=0; d<Hd; d++) wc[d] = w[d*128 + l];
  for (int i=l; i < 8*Hd; i += 128){
    size_t t = (size_t)node0*Hd + i;
    unsigned int e = enc[t];
    unsigned int bits = (e & 0x80000000u) ? (e ^ 0x80000000u) : ~e;
    float f = __uint_as_float(bits);
    if (isfinite(f)) f += b2[i & 63]; else f = 0.f;
    f = f > 0.f ? f : expm1f(f);
    xs[i] = f;
    X[t] = f;
    xb[t] = bf16rne(f);
    enc[t] = 0x007FFFFFu;           // re-arm for next emsg
  }
  __syncthreads();
  if (l < 8){
    float s = 0.f;
    #pragma unroll
    for (int d=0; d<Hd; d++){ float v = xs[l*Hd+d]; s = fmaf(v, v, s); }
    sq[node0 + l] = s;
  }
  #pragma unroll
  for (int n=0; n<8; n++){
    float s = 0.f;
    #pragma unroll
    for (int d=0; d<Hd; d++) s = fmaf(xs[n*Hd+d], wc[d], s);
    int node = node0 + n;
    if (l < 64) P[(size_t)node*64 + l] = s;
    else        Q[(size_t)node*64 + (l-64)] = s;
  }
}

// ---------- sq norms + bf16 copy of X (first static layer input path)
__global__ __launch_bounds__(256) void sqxb_kernel(const float* __restrict__ x,
        float* __restrict__ sq, unsigned short* __restrict__ xb){
  int t = blockIdx.x*256 + threadIdx.x;
  int node = t >> 6, l = t & 63;
  float v = x[t];
  xb[t] = bf16rne(v);
  float s = v*v;
  #pragma unroll
  for (int o=32; o; o>>=1) s += __shfl_xor(s, o, 64);
  if (l == 0) sq[node] = s;
}

// ---------- CSR build
__global__ void count_kernel(const int* __restrict__ ei, int* __restrict__ deg){
  int e = blockIdx.x*256 + threadIdx.x;
  atomicAdd(&deg[ei[En + e]], 1);
}

__global__ __launch_bounds__(1024) void scan_kernel(const int* __restrict__ deg,
        int* __restrict__ rowptr, int* __restrict__ cursor){
  __shared__ int ps[1024];
  int t = threadIdx.x;
  int base = t*64;
  int s = 0;
  for (int k=0;k<64;k++) s += deg[base+k];
  ps[t] = s; __syncthreads();
  for (int off=1; off<1024; off<<=1){
    int v = (t>=off) ? ps[t-off] : 0;
    __syncthreads();
    ps[t] += v;
    __syncthreads();
  }
  int run = (t>0) ? ps[t-1] : 0;
  for (int k=0;k<64;k++){
    rowptr[base+k] = run; cursor[base+k] = run;
    run += deg[base+k];
  }
  if (t==1023) rowptr[BNn] = run;
}

__global__ void scatter_kernel(const int* __restrict__ ei, int* __restrict__ cursor,
                               int* __restrict__ csrc, int* __restrict__ enid){
  int e = blockIdx.x*256 + threadIdx.x;
  int s = ei[e], d = ei[En + e];
  int pos = atomicAdd(&cursor[d], 1);
  csrc[pos] = s;
  enid[pos] = d;
}

// swizzled LDS address: row-major [*][stride bytes], byte ^= (row&7)<<4
#define SWZ16(base, row, stridep2, byteoff) \
  ((unsigned short*)((char*)(base) + ((((row) << (stridep2)) + (byteoff)) ^ (((row) & 7) << 4))))

// ---------- static EdgeConv v2: split-bf16 MFMA GEMM + Ct-LDS run-max epilogue
__global__ __launch_bounds__(256,3) void econv_gemm_kernel(
    const int* __restrict__ csrc, const int* __restrict__ enid,
    const float* __restrict__ P, const float* __restrict__ Q,
    const float* __restrict__ b1, const float* __restrict__ w2,
    unsigned int* __restrict__ enc){
  __shared__ __align__(16) char smem[49152];
  unsigned short* Ah = (unsigned short*)smem;            // [128][64] bf16 swz, 16384
  unsigned short* Al = (unsigned short*)(smem + 16384);  // 16384
  unsigned short* Wh = (unsigned short*)(smem + 32768);  // [64 n][64 k] bf16 swz, 8192
  unsigned short* Wl = (unsigned short*)(smem + 40960);  // 8192
  float* Ct = (float*)smem;                              // [64 ch][128 row] f32 overlay
  __shared__ int eids[256];
  int tid = threadIdx.x;
  int lane = tid & 63, w = tid >> 6;
  int e0 = ((blockIdx.x & 7)*640 + (blockIdx.x >> 3))*256;   // XCD-chunked (5120 wg)

  eids[tid] = enid[e0 + tid];
  // ---- stage W2 hi/lo transposed [n][k]
  #pragma unroll
  for (int z = 0; z < 16; z++){
    int idx = z*256 + tid;
    int k = idx >> 6, n = idx & 63;
    float f = w2[idx];
    unsigned short h = bf16rne(f);
    float fh = __uint_as_float((unsigned)h << 16);
    unsigned short l = bf16rne(f - fh);
    *SWZ16(Wh, n, 7, k*2) = h;
    *SWZ16(Wl, n, 7, k*2) = l;
  }

  #pragma unroll 1
  for (int hh = 0; hh < 2; hh++){
    int eh0 = e0 + hh*128;
    __syncthreads();          // prev-half Ct reads done; eids/W visible (hh=0)
    // ---- stage A = relu(P[i]+Q[j]+b1) -> bf16 hi/lo
    {
      int el = tid >> 1, kh2 = (tid & 1) * 32;
      int e = eh0 + el;
      int i = eids[hh*128 + el];
      int j = csrc[e];
      const float* Pr = P + (size_t)i*Hd + kh2;
      const float* Qr = Q + (size_t)j*Hd + kh2;
      const float* Br = b1 + kh2;
      #pragma unroll
      for (int m = 0; m < 4; m++){
        float4 pa = ((const float4*)Pr)[2*m], pb = ((const float4*)Pr)[2*m+1];
        float4 qa = ((const float4*)Qr)[2*m], qb = ((const float4*)Qr)[2*m+1];
        float4 ba = ((const float4*)Br)[2*m], bbv = ((const float4*)Br)[2*m+1];
        float a[8];
        a[0]=fmaxf(pa.x+qa.x+ba.x,0.f);  a[1]=fmaxf(pa.y+qa.y+ba.y,0.f);
        a[2]=fmaxf(pa.z+qa.z+ba.z,0.f);  a[3]=fmaxf(pa.w+qa.w+ba.w,0.f);
        a[4]=fmaxf(pb.x+qb.x+bbv.x,0.f); a[5]=fmaxf(pb.y+qb.y+bbv.y,0.f);
        a[6]=fmaxf(pb.z+qb.z+bbv.z,0.f); a[7]=fmaxf(pb.w+qb.w+bbv.w,0.f);
        unsigned hw[4], lw[4];
        #pragma unroll
        for (int t=0;t<4;t++){
          unsigned short h0 = bf16rne(a[2*t]);
          unsigned short h1 = bf16rne(a[2*t+1]);
          float f0 = __uint_as_float((unsigned)h0 << 16);
          float f1 = __uint_as_float((unsigned)h1 << 16);
          unsigned short l0 = bf16rne(a[2*t] - f0);
          unsigned short l1 = bf16rne(a[2*t+1] - f1);
          hw[t] = (unsigned)h0 | ((unsigned)h1 << 16);
          lw[t] = (unsigned)l0 | ((unsigned)l1 << 16);
        }
        uint4 hv = {hw[0], hw[1], hw[2], hw[3]};
        uint4 lv = {lw[0], lw[1], lw[2], lw[3]};
        *(uint4*)SWZ16(Ah, el, 7, (kh2 + 8*m)*2) = hv;
        *(uint4*)SWZ16(Al, el, 7, (kh2 + 8*m)*2) = lv;
      }
    }
    __syncthreads();
    // ---- MFMA: wave w computes rows [w*32, w*32+32) x 64 cols
    bf16x8 Af[2][2], Lf[2][2];
    #pragma unroll
    for (int mt=0; mt<2; mt++)
      #pragma unroll
      for (int s=0; s<2; s++){
        int row = w*32 + mt*16 + (lane & 15);
        Af[mt][s] = *(const bf16x8*)SWZ16(Ah, row, 7, (s*32 + (lane>>4)*8)*2);
        Lf[mt][s] = *(const bf16x8*)SWZ16(Al, row, 7, (s*32 + (lane>>4)*8)*2);
      }
    f32x4 acc[2][4];
    #pragma unroll
    for (int mt=0; mt<2; mt++)
      #pragma unroll
      for (int nt=0; nt<4; nt++)
        acc[mt][nt] = (f32x4){0.f,0.f,0.f,0.f};
    #pragma unroll
    for (int nt=0; nt<4; nt++){
      int n = nt*16 + (lane & 15);
      bf16x8 Bh0 = *(const bf16x8*)SWZ16(Wh, n, 7, ((lane>>4)*8)*2);
      bf16x8 Bh1 = *(const bf16x8*)SWZ16(Wh, n, 7, (32 + (lane>>4)*8)*2);
      bf16x8 Bl0 = *(const bf16x8*)SWZ16(Wl, n, 7, ((lane>>4)*8)*2);
      bf16x8 Bl1 = *(const bf16x8*)SWZ16(Wl, n, 7, (32 + (lane>>4)*8)*2);
      #pragma unroll
      for (int mt=0; mt<2; mt++){
        f32x4 a_ = acc[mt][nt];
        a_ = __builtin_amdgcn_mfma_f32_16x16x32_bf16(Af[mt][0], Bh0, a_, 0, 0, 0);
        a_ = __builtin_amdgcn_mfma_f32_16x16x32_bf16(Af[mt][1], Bh1, a_, 0, 0, 0);
        a_ = __builtin_amdgcn_mfma_f32_16x16x32_bf16(Af[mt][0], Bl0, a_, 0, 0, 0);
        a_ = __builtin_amdgcn_mfma_f32_16x16x32_bf16(Af[mt][1], Bl1, a_, 0, 0, 0);
        a_ = __builtin_amdgcn_mfma_f32_16x16x32_bf16(Lf[mt][0], Bh0, a_, 0, 0, 0);
        a_ = __builtin_amdgcn_mfma_f32_16x16x32_bf16(Lf[mt][1], Bh1, a_, 0, 0, 0);
        acc[mt][nt] = a_;
      }
    }
    __syncthreads();          // Ah/Al dead -> Ct overlay
    // ---- write C^T to LDS (swizzled)
    #pragma unroll
    for (int mt=0; mt<2; mt++){
      int rb = w*32 + mt*16 + (lane>>4)*4;
      #pragma unroll
      for (int nt=0; nt<4; nt++){
        int ch = nt*16 + (lane & 15);
        #pragma unroll
        for (int v=0; v<4; v++)
          Ct[ch*128 + ((rb+v) ^ (ch & 31))] = acc[mt][nt][v];
      }
    }
    __syncthreads();
    // ---- epilogue: per (ch, 32-row part) run-max over eids -> atomicMax(enc)
    {
      int ch = tid & 63, part = tid >> 6;
      int rbase = part*32;
      int cur = eids[hh*128 + rbase];
      float vmax = -INFINITY;
      #pragma unroll 1
      for (int r = 0; r < 32; r++){
        int row = rbase + r;
        int id = eids[hh*128 + row];
        float v = Ct[ch*128 + (row ^ (ch & 31))];
        if (id != cur){
          atomicMax(&enc[(size_t)cur*Hd + ch], enc_f32(vmax));
          vmax = -INFINITY; cur = id;
        }
        vmax = fmaxf(vmax, v);
      }
      atomicMax(&enc[(size_t)cur*Hd + ch], enc_f32(vmax));
    }
  }
}

// ---------- kNN: bf16-MFMA approx distances + per-quarter top-24 (u32 keys)
// v12 (R13, kept): registerized pending + merge-flush + bitonic warm-start.
#define KNN_MFLUSH(bm) do { \
  unsigned Lm[32]; \
  _Pragma("unroll") \
  for (int t=0;t<KK;t++) Lm[t] = kb[t]; \
  _Pragma("unroll") \
  for (int k2=2;k2<=8;k2<<=1) \
    _Pragma("unroll") \
    for (int j2=k2>>1;j2>0;j2>>=1) \
      _Pragma("unroll") \
      for (int i2=0;i2<8;i2++){ \
        int ixj=i2^j2; \
        if (ixj>i2){ \
          unsigned a=bm[i2], c=bm[ixj]; \
          unsigned lo = a<c?a:c, hi = a<c?c:a; \
          bool up = ((i2 & k2)==0); \
          bm[i2] = up?lo:hi; bm[ixj] = up?hi:lo; \
        } \
      } \
  _Pragma("unroll") \
  for (int t=0;t<8;t++) Lm[24+t] = bm[7-t]; \
  _Pragma("unroll") \
  for (int j2=16;j2>0;j2>>=1) \
    _Pragma("unroll") \
    for (int i2=0;i2<32;i2++){ \
      int ixj=i2^j2; \
      if (ixj>i2){ \
        unsigned a=Lm[i2], c=Lm[ixj]; \
        Lm[i2] = a<c?a:c; Lm[ixj] = a<c?c:a; \
      } \
    } \
  _Pragma("unroll") \
  for (int t=0;t<KK;t++) kb[t] = Lm[t]; \
  kbLast = kb[KK-1]; \
} while(0)

__global__ __launch_bounds__(256,4) void knn_kernel(
    const unsigned short* __restrict__ xb, const float* __restrict__ sq,
    unsigned short* __restrict__ cand){
  __shared__ __align__(16) unsigned short xjb[128*64];    // 16384 B (swizzled)
  __shared__ __align__(16) unsigned short Dt[64*128];     // 16384 B (u16 keys, swizzled)
  __shared__ float sqs[128];                              // 512 B  => 33280 B total

  int tid = threadIdx.x;
  int lane = tid & 63, w = tid >> 6;
  int bid = ((blockIdx.x & 7) << 7) | (blockIdx.x >> 3);  // XCD-chunked (1024 wg)
  int g  = bid >> 5;
  int r0 = (bid & 31) * 64;
  const unsigned short* xbg = xb + (size_t)g*Ng*Hd;
  const float* sg = sq + (size_t)g*Ng;

  int q = w;
  int prow = lane;
  int rw = w*16;

  // ---- A fragments direct from global (rows are L2-hot; no LDS staging)
  bf16x8 A0, A1;
  {
    int arow = r0 + rw + (lane & 15);
    A0 = *(const bf16x8*)(xbg + (size_t)arow*Hd +      (lane>>4)*8);
    A1 = *(const bf16x8*)(xbg + (size_t)arow*Hd + 32 + (lane>>4)*8);
  }
  // ---- stage xjb (swizzled) + sqs
  {
    int jr = tid >> 1, half = tid & 1;
    int jloc = (jr >> 5)*512 + (jr & 31);
    const uint4* src = (const uint4*)(xbg + (size_t)jloc*Hd + half*32);
    uint4 a = src[0], b = src[1], c2 = src[2], d2 = src[3];
    *(uint4*)SWZ16(xjb, jr, 7, half*64 +  0) = a;
    *(uint4*)SWZ16(xjb, jr, 7, half*64 + 16) = b;
    *(uint4*)SWZ16(xjb, jr, 7, half*64 + 32) = c2;
    *(uint4*)SWZ16(xjb, jr, 7, half*64 + 48) = d2;
    if (tid < 128) sqs[tid] = sg[(tid>>5)*512 + (tid&31)];
  }

  unsigned kb[KK];
  #pragma unroll
  for (int t=0;t<KK;t++) kb[t] = 0xFFFFFFFFu;
  unsigned kbLast = 0xFFFFFFFFu;

  __syncthreads();

  #pragma unroll 1
  for (int it = 0; it < 16; it++){
    uint4 pf0, pf1, pf2, pf3; float psq = 0.f;
    int itn = it + 1;
    int jr = tid >> 1, half = tid & 1;
    if (itn < 16){
      int jloc = (jr >> 5)*512 + itn*32 + (jr & 31);
      const uint4* src = (const uint4*)(xbg + (size_t)jloc*Hd + half*32);
      pf0 = src[0]; pf1 = src[1]; pf2 = src[2]; pf3 = src[3];
      if (tid < 128) psq = sg[(tid>>5)*512 + itn*32 + (tid&31)];
    }
    #pragma unroll
    for (int jb = 0; jb < 8; jb++){
      int brow = jb*16 + (lane & 15);
      bf16x8 B0 = *(const bf16x8*)SWZ16(xjb, brow, 7,      (lane>>4)*16);
      bf16x8 B1 = *(const bf16x8*)SWZ16(xjb, brow, 7, 64 + (lane>>4)*16);
      f32x4 acc = {0.f, 0.f, 0.f, 0.f};
      acc = __builtin_amdgcn_mfma_f32_16x16x32_bf16(A0, B0, acc, 0, 0, 0);
      acc = __builtin_amdgcn_mfma_f32_16x16x32_bf16(A1, B1, acc, 0, 0, 0);
      int col = jb*16 + (lane & 15);
      float sqv = sqs[col];
      int rbase = rw + (lane>>4)*4;
      #pragma unroll
      for (int v=0; v<4; v++){
        // sortable u16 encode of f = -2*dot + sqj  (top 16 bits of sign-flipped f32)
        float f = fmaf(acc[v], -2.f, sqv);
        unsigned u = __float_as_uint(f);
        unsigned t2 = ((unsigned)((int)u >> 31)) | 0x8000u;
        *SWZ16(Dt, rbase + v, 8, col*2) = (unsigned short)((u >> 16) ^ t2);
      }
    }
    __syncthreads();
    if (it == 0){
      // warm start: sort this lane's 32 keys (bitonic, registers), kb = smallest 24
      unsigned key[32];
      const char* dbase = (const char*)Dt + (prow << 8);
      unsigned m = (prow & 7) << 4;
      #pragma unroll
      for (int r4=0; r4<4; r4++){
        uint4 dv = *(const uint4*)(dbase + ((unsigned)(q*64 + r4*16) ^ m));
        int cb = q*512 + r4*8;
        key[r4*8+0] = (dv.x << 16) + (unsigned)(cb + 0);
        key[r4*8+1] = (dv.x & 0xFFFF0000u) | (unsigned)(cb + 1);
        key[r4*8+2] = (dv.y << 16) + (unsigned)(cb + 2);
        key[r4*8+3] = (dv.y & 0xFFFF0000u) | (unsigned)(cb + 3);
        key[r4*8+4] = (dv.z << 16) + (unsigned)(cb + 4);
        key[r4*8+5] = (dv.z & 0xFFFF0000u) | (unsigned)(cb + 5);
        key[r4*8+6] = (dv.w << 16) + (unsigned)(cb + 6);
        key[r4*8+7] = (dv.w & 0xFFFF0000u) | (unsigned)(cb + 7);
      }
      #pragma unroll
      for (int k2 = 2; k2 <= 32; k2 <<= 1){
        #pragma unroll
        for (int j2 = k2>>1; j2 > 0; j2 >>= 1){
          #pragma unroll
          for (int i2 = 0; i2 < 32; i2++){
            int ixj = i2 ^ j2;
            if (ixj > i2){
              unsigned a = key[i2], b = key[ixj];
              unsigned lo = a < b ? a : b;
              unsigned hi = a < b ? b : a;
              bool up = ((i2 & k2) == 0);
              key[i2]  = up ? lo : hi;
              key[ixj] = up ? hi : lo;
            }
          }
        }
      }
      #pragma unroll
      for (int t=0;t<KK;t++) kb[t] = key[t];
      kbLast = kb[KK-1];
    } else {
      int jbase0 = q*512 + it*32;
      const char* dbase = (const char*)Dt + (prow << 8);
      unsigned m = (prow & 7) << 4;
      #pragma unroll
      for (int r4=0; r4<4; r4++){
        uint4 dv = *(const uint4*)(dbase + ((unsigned)(q*64 + r4*16) ^ m));
        int cb = jbase0 + r4*8;
        unsigned k0 = (dv.x << 16) + (unsigned)(cb + 0);
        unsigned k1 = (dv.x & 0xFFFF0000u) | (unsigned)(cb + 1);
        unsigned k2v = (dv.y << 16) + (unsigned)(cb + 2);
        unsigned k3 = (dv.y & 0xFFFF0000u) | (unsigned)(cb + 3);
        unsigned k4 = (dv.z << 16) + (unsigned)(cb + 4);
        unsigned k5 = (dv.z & 0xFFFF0000u) | (unsigned)(cb + 5);
        unsigned k6 = (dv.w << 16) + (unsigned)(cb + 6);
        unsigned k7 = (dv.w & 0xFFFF0000u) | (unsigned)(cb + 7);
        unsigned bm[8];
        bm[0] = (k0 < kbLast) ? k0 : 0xFFFFFFFFu;
        bm[1] = (k1 < kbLast) ? k1 : 0xFFFFFFFFu;
        bm[2] = (k2v < kbLast) ? k2v : 0xFFFFFFFFu;
        bm[3] = (k3 < kbLast) ? k3 : 0xFFFFFFFFu;
        bm[4] = (k4 < kbLast) ? k4 : 0xFFFFFFFFu;
        bm[5] = (k5 < kbLast) ? k5 : 0xFFFFFFFFu;
        bm[6] = (k6 < kbLast) ? k6 : 0xFFFFFFFFu;
        bm[7] = (k7 < kbLast) ? k7 : 0xFFFFFFFFu;
        unsigned mn01 = bm[0] < bm[1] ? bm[0] : bm[1];
        unsigned mn23 = bm[2] < bm[3] ? bm[2] : bm[3];
        unsigned mn45 = bm[4] < bm[5] ? bm[4] : bm[5];
        unsigned mn67 = bm[6] < bm[7] ? bm[6] : bm[7];
        unsigned mn03 = mn01 < mn23 ? mn01 : mn23;
        unsigned mn47 = mn45 < mn67 ? mn45 : mn67;
        unsigned mn = mn03 < mn47 ? mn03 : mn47;
        if (__any(mn != 0xFFFFFFFFu)) KNN_MFLUSH(bm);
      }
    }
    if (itn < 16){
      *(uint4*)SWZ16(xjb, jr, 7, half*64 +  0) = pf0;
      *(uint4*)SWZ16(xjb, jr, 7, half*64 + 16) = pf1;
      *(uint4*)SWZ16(xjb, jr, 7, half*64 + 32) = pf2;
      *(uint4*)SWZ16(xjb, jr, 7, half*64 + 48) = pf3;
      if (tid < 128) sqs[tid] = psq;
    }
    __syncthreads();
  }
  size_t base = (size_t)(g*Ng + r0 + prow)*96 + q*24;
  #pragma unroll
  for (int t=0;t<KK;t++)
    cand[base + t] = (unsigned short)(kb[t] & 2047u);
}

// ---------- exact rerank v5 (R13): XCD-chunked + all-24-loads-in-flight
//   [R14 lesson: __launch_bounds__(256,4) split the unified reg file (VGPR=64 +
//    scratch spill, 2.1GB traffic). NEVER set min-waves >= 3 on reg-heavy kernels.]
__global__ __launch_bounds__(256,2) void rerank_kernel(const float* __restrict__ x,
        const unsigned short* __restrict__ cand, int* __restrict__ idx){
  __shared__ __align__(16) unsigned long long ks[4][96];
  int tid = threadIdx.x;
  int lane = tid & 63, w = tid >> 6;
  int bid = ((blockIdx.x & 7) << 11) | (blockIdx.x >> 3);   // XCD-chunked (16384 wg)
  int row = bid*4 + w;
  int g = row >> 11;
  const float* xg = x + (size_t)g*Ng*Hd;
  int chunk = lane & 3;        // 16B chunk within a row
  int cg = lane >> 2;          // candidate group 0..15
  const float* xr = x + (size_t)row*Hd;
  float4 xc[4];
  #pragma unroll
  for (int it2=0; it2<4; it2++) xc[it2] = *(const float4*)(xr + 16*it2 + 4*chunk);

  int js[6];
  #pragma unroll
  for (int p=0; p<6; p++) js[p] = cand[(size_t)row*96 + p*16 + cg];

  // phase 1: issue all 24 gathers (static indices -> registers, deep MLP)
  float4 bb[6][4];
  #pragma unroll
  for (int p=0; p<6; p++){
    const float* xj = xg + (size_t)js[p]*Hd;
    #pragma unroll
    for (int it2=0; it2<4; it2++) bb[p][it2] = *(const float4*)(xj + 16*it2 + 4*chunk);
  }
  // phase 2: reduce
  #pragma unroll
  for (int p=0; p<6; p++){
    float dot = 0.f, sqj = 0.f;
    #pragma unroll
    for (int it2=0; it2<4; it2++){
      float4 b = bb[p][it2];
      float4 a = xc[it2];
      dot = fmaf(a.x, b.x, dot); dot = fmaf(a.y, b.y, dot);
      dot = fmaf(a.z, b.z, dot); dot = fmaf(a.w, b.w, dot);
      sqj = fmaf(b.x, b.x, sqj); sqj = fmaf(b.y, b.y, sqj);
      sqj = fmaf(b.z, b.z, sqj); sqj = fmaf(b.w, b.w, sqj);
    }
    dot += __shfl_xor(dot, 1, 64); dot += __shfl_xor(dot, 2, 64);
    sqj += __shfl_xor(sqj, 1, 64); sqj += __shfl_xor(sqj, 2, 64);
    if (chunk == 0){
      float dist = fmaf(dot, -2.f, sqj);   // row-constant +sq_i dropped (order-invariant)
      ks[w][p*16 + cg] = ((unsigned long long)enc_f32(dist) << 32) | (unsigned)js[p];
    }
  }
  __syncthreads();
  unsigned long long k0 = ks[w][lane];
  unsigned long long k1 = (lane < 32) ? ks[w][64 + lane] : ~0ULL;
  int r0 = 0, r1 = 0;
  #pragma unroll
  for (int c=0;c<96;c+=2){
    unsigned long long a = ks[w][c], b = ks[w][c+1];
    r0 += (a < k0) + (b < k0);
    r1 += (a < k1) + (b < k1);
  }
  if (r0 < Kn) idx[(size_t)row*Kn + r0] = g*Ng + (int)(k0 & 2047ULL);
  if (lane < 32 && r1 < Kn) idx[(size_t)row*Kn + r1] = g*Ng + (int)(k1 & 2047ULL);
}

// ---------- dynamic EdgeConv stage 2 v2: split-bf16 MFMA GEMM (bf16x3)
__global__ __launch_bounds__(256,3) void emsg_kernel(
    const int* __restrict__ srcl,
    const float* __restrict__ P, const float* __restrict__ Q,
    const float* __restrict__ b1, const float* __restrict__ w2,
    unsigned int* __restrict__ enc){
  __shared__ __align__(16) char smem[49152];
  unsigned short* Ah = (unsigned short*)smem;            // [128][64] bf16 swz, 16384
  unsigned short* Al = (unsigned short*)(smem + 16384);  // 16384
  unsigned short* Wh = (unsigned short*)(smem + 32768);  // [64 n][64 k] bf16 swz, 8192
  unsigned short* Wl = (unsigned short*)(smem + 40960);  // 8192
  float* p0 = (float*)smem;                              // [64][33] f32 overlay on Ah/Al
  float* p1 = (float*)(smem + 8448);
  int tid = threadIdx.x;
  int lane = tid & 63, w = tid >> 6;
  int e0 = ((blockIdx.x & 7)*640 + (blockIdx.x >> 3))*256;   // XCD-chunked (5120 wg)

  // ---- stage W2 hi/lo transposed [n][k] (once; n = tid&63, k = z*4 + tid>>6)
  #pragma unroll
  for (int z = 0; z < 16; z++){
    int idx = z*256 + tid;
    int k = idx >> 6, n = idx & 63;
    float f = w2[idx];
    unsigned short h = bf16rne(f);
    float fh = __uint_as_float((unsigned)h << 16);
    unsigned short l = bf16rne(f - fh);
    *SWZ16(Wh, n, 7, k*2) = h;
    *SWZ16(Wl, n, 7, k*2) = l;
  }

  #pragma unroll 1
  for (int hh = 0; hh < 2; hh++){
    int eh0 = e0 + hh*128;
    __syncthreads();          // prev-half p-reads done; W stage visible
    // ---- stage A = relu(P[i]+Q[j]+b1) -> bf16 hi/lo (thread: edge tid>>1, k-half (tid&1)*32)
    {
      int el = tid >> 1, kh = (tid & 1) * 32;
      int e = eh0 + el;
      int i = e / Kn;
      int j = srcl[e];
      const float* Pr = P + (size_t)i*Hd + kh;
      const float* Qr = Q + (size_t)j*Hd + kh;
      const float* Br = b1 + kh;
      #pragma unroll
      for (int m = 0; m < 4; m++){
        float4 pa = ((const float4*)Pr)[2*m], pb = ((const float4*)Pr)[2*m+1];
        float4 qa = ((const float4*)Qr)[2*m], qb = ((const float4*)Qr)[2*m+1];
        float4 ba = ((const float4*)Br)[2*m], bbv = ((const float4*)Br)[2*m+1];
        float a[8];
        a[0]=fmaxf(pa.x+qa.x+ba.x,0.f);  a[1]=fmaxf(pa.y+qa.y+ba.y,0.f);
        a[2]=fmaxf(pa.z+qa.z+ba.z,0.f);  a[3]=fmaxf(pa.w+qa.w+ba.w,0.f);
        a[4]=fmaxf(pb.x+qb.x+bbv.x,0.f); a[5]=fmaxf(pb.y+qb.y+bbv.y,0.f);
        a[6]=fmaxf(pb.z+qb.z+bbv.z,0.f); a[7]=fmaxf(pb.w+qb.w+bbv.w,0.f);
        unsigned hw[4], lw[4];
        #pragma unroll
        for (int t=0;t<4;t++){
          unsigned short h0 = bf16rne(a[2*t]);
          unsigned short h1 = bf16rne(a[2*t+1]);
          float f0 = __uint_as_float((unsigned)h0 << 16);
          float f1 = __uint_as_float((unsigned)h1 << 16);
          unsigned short l0 = bf16rne(a[2*t] - f0);
          unsigned short l1 = bf16rne(a[2*t+1] - f1);
          hw[t] = (unsigned)h0 | ((unsigned)h1 << 16);
          lw[t] = (unsigned)l0 | ((unsigned)l1 << 16);
        }
        uint4 hv = {hw[0], hw[1], hw[2], hw[3]};
        uint4 lv = {lw[0], lw[1], lw[2], lw[3]};
        *(uint4*)SWZ16(Ah, el, 7, (kh + 8*m)*2) = hv;
        *(uint4*)SWZ16(Al, el, 7, (kh + 8*m)*2) = lv;
      }
    }
    __syncthreads();
    // ---- MFMA: wave w computes rows [w*32, w*32+32) x 64 cols
    bf16x8 Af[2][2], Lf[2][2];
    #pragma unroll
    for (int mt=0; mt<2; mt++)
      #pragma unroll
      for (int s=0; s<2; s++){
        int row = w*32 + mt*16 + (lane & 15);
        Af[mt][s] = *(const bf16x8*)SWZ16(Ah, row, 7, (s*32 + (lane>>4)*8)*2);
        Lf[mt][s] = *(const bf16x8*)SWZ16(Al, row, 7, (s*32 + (lane>>4)*8)*2);
      }
    f32x4 acc[2][4];
    #pragma unroll
    for (int mt=0; mt<2; mt++)
      #pragma unroll
      for (int nt=0; nt<4; nt++)
        acc[mt][nt] = (f32x4){0.f,0.f,0.f,0.f};
    #pragma unroll
    for (int nt=0; nt<4; nt++){
      int n = nt*16 + (lane & 15);
      bf16x8 Bh0 = *(const bf16x8*)SWZ16(Wh, n, 7, ((lane>>4)*8)*2);
      bf16x8 Bh1 = *(const bf16x8*)SWZ16(Wh, n, 7, (32 + (lane>>4)*8)*2);
      bf16x8 Bl0 = *(const bf16x8*)SWZ16(Wl, n, 7, ((lane>>4)*8)*2);
      bf16x8 Bl1 = *(const bf16x8*)SWZ16(Wl, n, 7, (32 + (lane>>4)*8)*2);
      #pragma unroll
      for (int mt=0; mt<2; mt++){
        f32x4 a_ = acc[mt][nt];
        a_ = __builtin_amdgcn_mfma_f32_16x16x32_bf16(Af[mt][0], Bh0, a_, 0, 0, 0);
        a_ = __builtin_amdgcn_mfma_f32_16x16x32_bf16(Af[mt][1], Bh1, a_, 0, 0, 0);
        a_ = __builtin_amdgcn_mfma_f32_16x16x32_bf16(Af[mt][0], Bl0, a_, 0, 0, 0);
        a_ = __builtin_amdgcn_mfma_f32_16x16x32_bf16(Af[mt][1], Bl1, a_, 0, 0, 0);
        a_ = __builtin_amdgcn_mfma_f32_16x16x32_bf16(Lf[mt][0], Bh0, a_, 0, 0, 0);
        a_ = __builtin_amdgcn_mfma_f32_16x16x32_bf16(Lf[mt][1], Bh1, a_, 0, 0, 0);
        acc[mt][nt] = a_;
      }
    }
    __syncthreads();          // Ah/Al dead -> p0/p1 overlay
    // ---- p-writes: 4-row chunks, <=2 nodes per chunk (4 < Kn)
    #pragma unroll
    for (int mt=0; mt<2; mt++){
      int rb = w*32 + mt*16 + (lane>>4)*4;
      int rbg = eh0 + rb;
      int nd0 = rbg / Kn;
      int split = (nd0+1)*Kn - rbg; if (split > 4) split = 4;
      int cm = rb >> 2;
      #pragma unroll
      for (int nt=0; nt<4; nt++){
        int ch = nt*16 + (lane & 15);
        float s0v = -INFINITY, s1v = -INFINITY;
        #pragma unroll
        for (int v=0; v<4; v++){
          float val = acc[mt][nt][v];
          if (v < split) s0v = fmaxf(s0v, val); else s1v = fmaxf(s1v, val);
        }
        p0[ch*33 + cm] = s0v;
        p1[ch*33 + cm] = s1v;
      }
    }
    __syncthreads();
    // ---- reduce + atomicMax
    int nfirst = eh0 / Kn;
    int ncnt = (eh0 + 127) / Kn - nfirst + 1;
    int ch = tid & 63;
    for (int ln = tid >> 6; ln < ncnt; ln += 4){
      int nd = nfirst + ln;
      int glo = nd*Kn;      if (glo < eh0)     glo = eh0;
      int ghi = nd*Kn + Kn; if (ghi > eh0+128) ghi = eh0+128;
      int mlo = (glo - eh0) >> 2, mhi = (ghi - 1 - eh0) >> 2;
      float v = -INFINITY;
      for (int mm = mlo; mm <= mhi; mm++){
        int bn = (eh0 + 4*mm) / Kn;
        if (bn == nd)     v = fmaxf(v, p0[ch*33 + mm]);
        if (bn + 1 == nd) v = fmaxf(v, p1[ch*33 + mm]);
      }
      atomicMax(&enc[(size_t)nd*Hd + ch], enc_f32(v));
    }
  }
}

// ---------- final decode (no ELU): enc -> float + b2
__global__ __launch_bounds__(256) void decode_kernel(const unsigned int* __restrict__ enc,
         const float* __restrict__ b2, float* __restrict__ x){
  int t = blockIdx.x*256 + threadIdx.x;
  unsigned int e = enc[t];
  unsigned int bits = (e & 0x80000000u) ? (e ^ 0x80000000u) : ~e;
  float f = __uint_as_float(bits);
  if (isfinite(f)) f += b2[t & 63]; else f = 0.f;
  x[t] = f;
}

__global__ __launch_bounds__(64) void final_kernel(const float* __restrict__ h,
        const float* __restrict__ w, const float* __restrict__ bias,
        float* __restrict__ out){
  __shared__ float xs[Hd];
  int c = threadIdx.x;
  float wc[Hd];
  float bc = 0.f;
  if (c < Cd){
    #pragma unroll
    for (int d=0; d<Hd; d++) wc[d] = w[d*Cd + c];
    bc = bias[c];
  }
  for (int i = blockIdx.x; i < BNn; i += gridDim.x){
    __syncthreads();
    xs[c] = h[(size_t)i*Hd + c];
    __syncthreads();
    if (c < Cd){
      float s = bc;
      #pragma unroll
      for (int d=0; d<Hd; d++) s = fmaf(xs[d], wc[d], s);
      out[(size_t)i*Cd + c] = s;
    }
  }
}

extern "C" void kernel_launch(void* const* d_in, const int* in_sizes, int n_in,
                              void* d_out, int out_size, void* d_ws, size_t ws_size,
                              hipStream_t stream){
  const float* x0   = (const float*)d_in[0];
  const int*   ei   = (const int*)d_in[1];
  const float* c1w1 = (const float*)d_in[3];
  const float* c1b1 = (const float*)d_in[4];
  const float* c1w2 = (const float*)d_in[5];
  const float* c1b2 = (const float*)d_in[6];
  const float* d1w1 = (const float*)d_in[7];
  const float* d1b1 = (const float*)d_in[8];
  const float* d1w2 = (const float*)d_in[9];
  const float* d1b2 = (const float*)d_in[10];
  const float* d2w1 = (const float*)d_in[11];
  const float* d2b1 = (const float*)d_in[12];
  const float* d2w2 = (const float*)d_in[13];
  const float* d2b2 = (const float*)d_in[14];
  const float* linw = (const float*)d_in[15];
  const float* linb = (const float*)d_in[16];
  float* out = (float*)d_out;

  char* ws = (char*)d_ws;
  size_t off = 0;
  auto alloc = [&](size_t bytes)->char*{
    char* p = ws + off; off += (bytes + 255) & ~(size_t)255; return p;
  };
  float*        X    = (float*)alloc(sizeof(float)*(size_t)BNn*Hd);
  float*        P    = (float*)alloc(sizeof(float)*(size_t)BNn*Hd);
  float*        Q    = (float*)alloc(sizeof(float)*(size_t)BNn*Hd);
  float*        H2   = (float*)alloc(sizeof(float)*(size_t)BNn*Hd);  // aliases XB, ENID
  unsigned int* ENC  = (unsigned int*)alloc(sizeof(unsigned)*(size_t)BNn*Hd); // aliases CAND
  int*          SHRD = (int*)alloc(sizeof(int)*(size_t)En);   // CSRC, later IDX
  int*          DEG  = (int*)alloc(sizeof(int)*BNn);
  int*          RPTR = (int*)alloc(sizeof(int)*(BNn+1));
  int*          CUR  = (int*)alloc(sizeof(int)*BNn);
  float*        SQ   = (float*)alloc(sizeof(float)*BNn);
  float*        WPQ0 = (float*)alloc(sizeof(float)*3*128);
  float*        WPQ1 = (float*)alloc(sizeof(float)*64*128);
  float*        WPQ2 = (float*)alloc(sizeof(float)*64*128);
  int*            CSRC = SHRD;
  int*            IDX  = SHRD;
  int*            ENID = (int*)H2;
  unsigned short* XB   = (unsigned short*)H2;
  unsigned short* CAND = (unsigned short*)ENC;
  (void)ws_size; (void)in_sizes; (void)n_in; (void)out_size;

  // static EdgeConv: CSR sort + edge-batched MFMA GEMM + run-max
  prep_w_kernel<<<BNn/256, 256, 0, stream>>>(c1w1, d1w1, d2w1, WPQ0, WPQ1, WPQ2, DEG);
  count_kernel<<<En/256, 256, 0, stream>>>(ei, DEG);
  gemm_pq_kernel<3><<<BNn/8, 128, 0, stream>>>(x0, WPQ0, P, Q);
  scan_kernel<<<1, 1024, 0, stream>>>(DEG, RPTR, CUR);
  scatter_kernel<<<En/256, 256, 0, stream>>>(ei, CUR, CSRC, ENID);
  init_enc_kernel<<<BNn*Hd/256, 256, 0, stream>>>(ENC);
  econv_gemm_kernel<<<En/256, 256, 0, stream>>>(CSRC, ENID, P, Q, c1b1, c1w2, ENC);

  // dynamic layer 1 (fused decode+gemm re-arms ENC -> no init_enc)
  decode_gemm_pq_kernel<<<BNn/8, 128, 0, stream>>>(ENC, c1b2, WPQ1, X, SQ, XB, P, Q);
  knn_kernel<<<Bg*32, 256, 0, stream>>>(XB, SQ, CAND);
  rerank_kernel<<<BNn/4, 256, 0, stream>>>(X, CAND, IDX);
  emsg_kernel<<<En/256, 256, 0, stream>>>(IDX, P, Q, d1b1, d1w2, ENC);

  // dynamic layer 2
  decode_gemm_pq_kernel<<<BNn/8, 128, 0, stream>>>(ENC, d1b2, WPQ2, X, SQ, XB, P, Q);
  knn_kernel<<<Bg*32, 256, 0, stream>>>(XB, SQ, CAND);
  rerank_kernel<<<BNn/4, 256, 0, stream>>>(X, CAND, IDX);
  emsg_kernel<<<En/256, 256, 0, stream>>>(IDX, P, Q, d2b1, d2w2, ENC);
  decode_kernel<<<BNn*Hd/256, 256, 0, stream>>>(ENC, d2b2, H2);

  final_kernel<<<8192, 64, 0, stream>>>(H2, linw, linb, out);
}

// Round 17
// 1193.775 us; speedup vs baseline: 1.5170x; 1.0109x over previous
//
#include <hip/hip_runtime.h>
#include <math.h>

#define Bg 32
#define Ng 2048
#define Kn 20
#define BNn (Bg*Ng)
#define En (BNn*Kn)
#define Hd 64
#define Cd 40

// knn-mfma params
#define KK 24            // approx top-K kept per j-quarter (96 cands/row)

typedef __attribute__((ext_vector_type(8))) short bf16x8;
typedef __attribute__((ext_vector_type(4))) float f32x4;

__device__ __forceinline__ unsigned enc_f32(float f){
  unsigned u = __float_as_uint(f);
  return ((int)u < 0) ? ~u : (u | 0x80000000u);
}

__device__ __forceinline__ unsigned short bf16rne(float f){
  unsigned u = __float_as_uint(f);
  return (unsigned short)((u + 0x7FFFu + ((u >> 16) & 1u)) >> 16);
}

// ---------- weight prep + DEG zero (fused; grid = BNn/256 = 256 blocks)
__global__ void prep_w_kernel(const float* __restrict__ w1c, const float* __restrict__ w1d1,
                              const float* __restrict__ w1d2,
                              float* __restrict__ wpq0, float* __restrict__ wpq1,
                              float* __restrict__ wpq2, int* __restrict__ deg){
  int t = blockIdx.x*256 + threadIdx.x;
  deg[t] = 0;                       // t < BNn by grid construction
  if (t < 3*128){
    int d = t >> 7, l = t & 127;
    wpq0[t] = (l < 64) ? (w1c[d*64 + l] - w1c[(d+3)*64 + l]) : w1c[(d+3)*64 + (l-64)];
  }
  if (t < 64*128){
    int d = t >> 7, l = t & 127;
    wpq1[t] = (l < 64) ? (w1d1[d*64 + l] - w1d1[(d+64)*64 + l]) : w1d1[(d+64)*64 + (l-64)];
    wpq2[t] = (l < 64) ? (w1d2[d*64 + l] - w1d2[(d+64)*64 + l]) : w1d2[(d+64)*64 + (l-64)];
  }
}

__global__ void init_enc_kernel(unsigned int* __restrict__ enc){
  enc[blockIdx.x*256 + threadIdx.x] = 0x007FFFFFu;   // enc(-inf)
}

// ---------- X[BN,D] @ wpq[D,128] -> P,Q  (static layer, D=3)
template<int D>
__global__ __launch_bounds__(128) void gemm_pq_kernel(const float* __restrict__ x,
                               const float* __restrict__ w,
                               float* __restrict__ P, float* __restrict__ Q){
  __shared__ float xs[8*D];
  int l = threadIdx.x;
  int node0 = blockIdx.x*8;
  float wc[D];
  #pragma unroll
  for (int d=0; d<D; d++) wc[d] = w[d*128 + l];
  for (int i=l; i < 8*D; i += 128) xs[i] = x[(size_t)node0*D + i];
  __syncthreads();
  #pragma unroll
  for (int n=0; n<8; n++){
    float s = 0.f;
    #pragma unroll
    for (int d=0; d<D; d++) s = fmaf(xs[n*D+d], wc[d], s);
    int node = node0 + n;
    if (l < 64) P[(size_t)node*64 + l] = s;
    else        Q[(size_t)node*64 + (l-64)] = s;
  }
}

// ---------- fused: decode(+b2,+ELU) from ENC -> X/XB/SQ + re-arm ENC + P,Q GEMM
__global__ __launch_bounds__(128) void decode_gemm_pq_kernel(
    unsigned int* __restrict__ enc, const float* __restrict__ b2,
    const float* __restrict__ w,
    float* __restrict__ X, float* __restrict__ sq, unsigned short* __restrict__ xb,
    float* __restrict__ P, float* __restrict__ Q){
  __shared__ float xs[8*Hd];
  int l = threadIdx.x;
  int node0 = blockIdx.x*8;
  float wc[Hd];
  #pragma unroll
  for (int d=0; d<Hd; d++) wc[d] = w[d*128 + l];
  for (int i=l; i < 8*Hd; i += 128){
    size_t t = (size_t)node0*Hd + i;
    unsigned int e = enc[t];
    unsigned int bits = (e & 0x80000000u) ? (e ^ 0x80000000u) : ~e;
    float f = __uint_as_float(bits);
    if (isfinite(f)) f += b2[i & 63]; else f = 0.f;
    f = f > 0.f ? f : expm1f(f);
    xs[i] = f;
    X[t] = f;
    xb[t] = bf16rne(f);
    enc[t] = 0x007FFFFFu;           // re-arm for next emsg (CAND-alias clobber is
                                    // benign: cand words < enc_f32 of any real value)
  }
  __syncthreads();
  if (l < 8){
    float s = 0.f;
    #pragma unroll
    for (int d=0; d<Hd; d++){ float v = xs[l*Hd+d]; s = fmaf(v, v, s); }
    sq[node0 + l] = s;
  }
  #pragma unroll
  for (int n=0; n<8; n++){
    float s = 0.f;
    #pragma unroll
    for (int d=0; d<Hd; d++) s = fmaf(xs[n*Hd+d], wc[d], s);
    int node = node0 + n;
    if (l < 64) P[(size_t)node*64 + l] = s;
    else        Q[(size_t)node*64 + (l-64)] = s;
  }
}

// ---------- sq norms + bf16 copy of X (first static layer input path)
__global__ __launch_bounds__(256) void sqxb_kernel(const float* __restrict__ x,
        float* __restrict__ sq, unsigned short* __restrict__ xb){
  int t = blockIdx.x*256 + threadIdx.x;
  int node = t >> 6, l = t & 63;
  float v = x[t];
  xb[t] = bf16rne(v);
  float s = v*v;
  #pragma unroll
  for (int o=32; o; o>>=1) s += __shfl_xor(s, o, 64);
  if (l == 0) sq[node] = s;
}

// ---------- CSR build
__global__ void count_kernel(const int* __restrict__ ei, int* __restrict__ deg){
  int e = blockIdx.x*256 + threadIdx.x;
  atomicAdd(&deg[ei[En + e]], 1);
}

__global__ __launch_bounds__(1024) void scan_kernel(const int* __restrict__ deg,
        int* __restrict__ rowptr, int* __restrict__ cursor){
  __shared__ int ps[1024];
  int t = threadIdx.x;
  int base = t*64;
  int s = 0;
  for (int k=0;k<64;k++) s += deg[base+k];
  ps[t] = s; __syncthreads();
  for (int off=1; off<1024; off<<=1){
    int v = (t>=off) ? ps[t-off] : 0;
    __syncthreads();
    ps[t] += v;
    __syncthreads();
  }
  int run = (t>0) ? ps[t-1] : 0;
  for (int k=0;k<64;k++){
    rowptr[base+k] = run; cursor[base+k] = run;
    run += deg[base+k];
  }
  if (t==1023) rowptr[BNn] = run;
}

__global__ void scatter_kernel(const int* __restrict__ ei, int* __restrict__ cursor,
                               int* __restrict__ csrc, int* __restrict__ enid){
  int e = blockIdx.x*256 + threadIdx.x;
  int s = ei[e], d = ei[En + e];
  int pos = atomicAdd(&cursor[d], 1);
  csrc[pos] = s;
  enid[pos] = d;
}

// swizzled LDS address: row-major [*][stride bytes], byte ^= (row&7)<<4
#define SWZ16(base, row, stridep2, byteoff) \
  ((unsigned short*)((char*)(base) + ((((row) << (stridep2)) + (byteoff)) ^ (((row) & 7) << 4))))

// ---------- static EdgeConv v2: split-bf16 MFMA GEMM + Ct-LDS run-max epilogue
__global__ __launch_bounds__(256,3) void econv_gemm_kernel(
    const int* __restrict__ csrc, const int* __restrict__ enid,
    const float* __restrict__ P, const float* __restrict__ Q,
    const float* __restrict__ b1, const float* __restrict__ w2,
    unsigned int* __restrict__ enc){
  __shared__ __align__(16) char smem[49152];
  unsigned short* Ah = (unsigned short*)smem;            // [128][64] bf16 swz, 16384
  unsigned short* Al = (unsigned short*)(smem + 16384);  // 16384
  unsigned short* Wh = (unsigned short*)(smem + 32768);  // [64 n][64 k] bf16 swz, 8192
  unsigned short* Wl = (unsigned short*)(smem + 40960);  // 8192
  float* Ct = (float*)smem;                              // [64 ch][128 row] f32 overlay
  __shared__ int eids[256];
  int tid = threadIdx.x;
  int lane = tid & 63, w = tid >> 6;
  int e0 = ((blockIdx.x & 7)*640 + (blockIdx.x >> 3))*256;   // XCD-chunked (5120 wg)

  eids[tid] = enid[e0 + tid];
  // ---- stage W2 hi/lo transposed [n][k]
  #pragma unroll
  for (int z = 0; z < 16; z++){
    int idx = z*256 + tid;
    int k = idx >> 6, n = idx & 63;
    float f = w2[idx];
    unsigned short h = bf16rne(f);
    float fh = __uint_as_float((unsigned)h << 16);
    unsigned short l = bf16rne(f - fh);
    *SWZ16(Wh, n, 7, k*2) = h;
    *SWZ16(Wl, n, 7, k*2) = l;
  }

  #pragma unroll 1
  for (int hh = 0; hh < 2; hh++){
    int eh0 = e0 + hh*128;
    __syncthreads();          // prev-half Ct reads done; eids/W visible (hh=0)
    // ---- stage A = relu(P[i]+Q[j]+b1) -> bf16 hi/lo
    {
      int el = tid >> 1, kh2 = (tid & 1) * 32;
      int e = eh0 + el;
      int i = eids[hh*128 + el];
      int j = csrc[e];
      const float* Pr = P + (size_t)i*Hd + kh2;
      const float* Qr = Q + (size_t)j*Hd + kh2;
      const float* Br = b1 + kh2;
      #pragma unroll
      for (int m = 0; m < 4; m++){
        float4 pa = ((const float4*)Pr)[2*m], pb = ((const float4*)Pr)[2*m+1];
        float4 qa = ((const float4*)Qr)[2*m], qb = ((const float4*)Qr)[2*m+1];
        float4 ba = ((const float4*)Br)[2*m], bbv = ((const float4*)Br)[2*m+1];
        float a[8];
        a[0]=fmaxf(pa.x+qa.x+ba.x,0.f);  a[1]=fmaxf(pa.y+qa.y+ba.y,0.f);
        a[2]=fmaxf(pa.z+qa.z+ba.z,0.f);  a[3]=fmaxf(pa.w+qa.w+ba.w,0.f);
        a[4]=fmaxf(pb.x+qb.x+bbv.x,0.f); a[5]=fmaxf(pb.y+qb.y+bbv.y,0.f);
        a[6]=fmaxf(pb.z+qb.z+bbv.z,0.f); a[7]=fmaxf(pb.w+qb.w+bbv.w,0.f);
        unsigned hw[4], lw[4];
        #pragma unroll
        for (int t=0;t<4;t++){
          unsigned short h0 = bf16rne(a[2*t]);
          unsigned short h1 = bf16rne(a[2*t+1]);
          float f0 = __uint_as_float((unsigned)h0 << 16);
          float f1 = __uint_as_float((unsigned)h1 << 16);
          unsigned short l0 = bf16rne(a[2*t] - f0);
          unsigned short l1 = bf16rne(a[2*t+1] - f1);
          hw[t] = (unsigned)h0 | ((unsigned)h1 << 16);
          lw[t] = (unsigned)l0 | ((unsigned)l1 << 16);
        }
        uint4 hv = {hw[0], hw[1], hw[2], hw[3]};
        uint4 lv = {lw[0], lw[1], lw[2], lw[3]};
        *(uint4*)SWZ16(Ah, el, 7, (kh2 + 8*m)*2) = hv;
        *(uint4*)SWZ16(Al, el, 7, (kh2 + 8*m)*2) = lv;
      }
    }
    __syncthreads();
    // ---- MFMA: wave w computes rows [w*32, w*32+32) x 64 cols
    bf16x8 Af[2][2], Lf[2][2];
    #pragma unroll
    for (int mt=0; mt<2; mt++)
      #pragma unroll
      for (int s=0; s<2; s++){
        int row = w*32 + mt*16 + (lane & 15);
        Af[mt][s] = *(const bf16x8*)SWZ16(Ah, row, 7, (s*32 + (lane>>4)*8)*2);
        Lf[mt][s] = *(const bf16x8*)SWZ16(Al, row, 7, (s*32 + (lane>>4)*8)*2);
      }
    f32x4 acc[2][4];
    #pragma unroll
    for (int mt=0; mt<2; mt++)
      #pragma unroll
      for (int nt=0; nt<4; nt++)
        acc[mt][nt] = (f32x4){0.f,0.f,0.f,0.f};
    #pragma unroll
    for (int nt=0; nt<4; nt++){
      int n = nt*16 + (lane & 15);
      bf16x8 Bh0 = *(const bf16x8*)SWZ16(Wh, n, 7, ((lane>>4)*8)*2);
      bf16x8 Bh1 = *(const bf16x8*)SWZ16(Wh, n, 7, (32 + (lane>>4)*8)*2);
      bf16x8 Bl0 = *(const bf16x8*)SWZ16(Wl, n, 7, ((lane>>4)*8)*2);
      bf16x8 Bl1 = *(const bf16x8*)SWZ16(Wl, n, 7, (32 + (lane>>4)*8)*2);
      #pragma unroll
      for (int mt=0; mt<2; mt++){
        f32x4 a_ = acc[mt][nt];
        a_ = __builtin_amdgcn_mfma_f32_16x16x32_bf16(Af[mt][0], Bh0, a_, 0, 0, 0);
        a_ = __builtin_amdgcn_mfma_f32_16x16x32_bf16(Af[mt][1], Bh1, a_, 0, 0, 0);
        a_ = __builtin_amdgcn_mfma_f32_16x16x32_bf16(Af[mt][0], Bl0, a_, 0, 0, 0);
        a_ = __builtin_amdgcn_mfma_f32_16x16x32_bf16(Af[mt][1], Bl1, a_, 0, 0, 0);
        a_ = __builtin_amdgcn_mfma_f32_16x16x32_bf16(Lf[mt][0], Bh0, a_, 0, 0, 0);
        a_ = __builtin_amdgcn_mfma_f32_16x16x32_bf16(Lf[mt][1], Bh1, a_, 0, 0, 0);
        acc[mt][nt] = a_;
      }
    }
    __syncthreads();          // Ah/Al dead -> Ct overlay
    // ---- write C^T to LDS (swizzled)
    #pragma unroll
    for (int mt=0; mt<2; mt++){
      int rb = w*32 + mt*16 + (lane>>4)*4;
      #pragma unroll
      for (int nt=0; nt<4; nt++){
        int ch = nt*16 + (lane & 15);
        #pragma unroll
        for (int v=0; v<4; v++)
          Ct[ch*128 + ((rb+v) ^ (ch & 31))] = acc[mt][nt][v];
      }
    }
    __syncthreads();
    // ---- epilogue: per (ch, 32-row part) run-max over eids -> atomicMax(enc)
    {
      int ch = tid & 63, part = tid >> 6;
      int rbase = part*32;
      int cur = eids[hh*128 + rbase];
      float vmax = -INFINITY;
      #pragma unroll 1
      for (int r = 0; r < 32; r++){
        int row = rbase + r;
        int id = eids[hh*128 + row];
        float v = Ct[ch*128 + (row ^ (ch & 31))];
        if (id != cur){
          atomicMax(&enc[(size_t)cur*Hd + ch], enc_f32(vmax));
          vmax = -INFINITY; cur = id;
        }
        vmax = fmaxf(vmax, v);
      }
      atomicMax(&enc[(size_t)cur*Hd + ch], enc_f32(vmax));
    }
  }
}

// ---------- kNN: bf16-MFMA approx distances + per-quarter top-24 (u32 keys)
// v12 (R13, kept): registerized pending + merge-flush + bitonic warm-start.
#define KNN_MFLUSH(bm) do { \
  unsigned Lm[32]; \
  _Pragma("unroll") \
  for (int t=0;t<KK;t++) Lm[t] = kb[t]; \
  _Pragma("unroll") \
  for (int k2=2;k2<=8;k2<<=1) \
    _Pragma("unroll") \
    for (int j2=k2>>1;j2>0;j2>>=1) \
      _Pragma("unroll") \
      for (int i2=0;i2<8;i2++){ \
        int ixj=i2^j2; \
        if (ixj>i2){ \
          unsigned a=bm[i2], c=bm[ixj]; \
          unsigned lo = a<c?a:c, hi = a<c?c:a; \
          bool up = ((i2 & k2)==0); \
          bm[i2] = up?lo:hi; bm[ixj] = up?hi:lo; \
        } \
      } \
  _Pragma("unroll") \
  for (int t=0;t<8;t++) Lm[24+t] = bm[7-t]; \
  _Pragma("unroll") \
  for (int j2=16;j2>0;j2>>=1) \
    _Pragma("unroll") \
    for (int i2=0;i2<32;i2++){ \
      int ixj=i2^j2; \
      if (ixj>i2){ \
        unsigned a=Lm[i2], c=Lm[ixj]; \
        Lm[i2] = a<c?a:c; Lm[ixj] = a<c?c:a; \
      } \
    } \
  _Pragma("unroll") \
  for (int t=0;t<KK;t++) kb[t] = Lm[t]; \
  kbLast = kb[KK-1]; \
} while(0)

__global__ __launch_bounds__(256,4) void knn_kernel(
    const unsigned short* __restrict__ xb, const float* __restrict__ sq,
    unsigned short* __restrict__ cand){
  __shared__ __align__(16) unsigned short xjb[128*64];    // 16384 B (swizzled)
  __shared__ __align__(16) unsigned short Dt[64*128];     // 16384 B (u16 keys, swizzled)
  __shared__ float sqs[128];                              // 512 B  => 33280 B total

  int tid = threadIdx.x;
  int lane = tid & 63, w = tid >> 6;
  int bid = ((blockIdx.x & 7) << 7) | (blockIdx.x >> 3);  // XCD-chunked (1024 wg)
  int g  = bid >> 5;
  int r0 = (bid & 31) * 64;
  const unsigned short* xbg = xb + (size_t)g*Ng*Hd;
  const float* sg = sq + (size_t)g*Ng;

  int q = w;
  int prow = lane;
  int rw = w*16;

  // ---- A fragments direct from global (rows are L2-hot; no LDS staging)
  bf16x8 A0, A1;
  {
    int arow = r0 + rw + (lane & 15);
    A0 = *(const bf16x8*)(xbg + (size_t)arow*Hd +      (lane>>4)*8);
    A1 = *(const bf16x8*)(xbg + (size_t)arow*Hd + 32 + (lane>>4)*8);
  }
  // ---- stage xjb (swizzled) + sqs
  {
    int jr = tid >> 1, half = tid & 1;
    int jloc = (jr >> 5)*512 + (jr & 31);
    const uint4* src = (const uint4*)(xbg + (size_t)jloc*Hd + half*32);
    uint4 a = src[0], b = src[1], c2 = src[2], d2 = src[3];
    *(uint4*)SWZ16(xjb, jr, 7, half*64 +  0) = a;
    *(uint4*)SWZ16(xjb, jr, 7, half*64 + 16) = b;
    *(uint4*)SWZ16(xjb, jr, 7, half*64 + 32) = c2;
    *(uint4*)SWZ16(xjb, jr, 7, half*64 + 48) = d2;
    if (tid < 128) sqs[tid] = sg[(tid>>5)*512 + (tid&31)];
  }

  unsigned kb[KK];
  #pragma unroll
  for (int t=0;t<KK;t++) kb[t] = 0xFFFFFFFFu;
  unsigned kbLast = 0xFFFFFFFFu;

  __syncthreads();

  #pragma unroll 1
  for (int it = 0; it < 16; it++){
    uint4 pf0, pf1, pf2, pf3; float psq = 0.f;
    int itn = it + 1;
    int jr = tid >> 1, half = tid & 1;
    if (itn < 16){
      int jloc = (jr >> 5)*512 + itn*32 + (jr & 31);
      const uint4* src = (const uint4*)(xbg + (size_t)jloc*Hd + half*32);
      pf0 = src[0]; pf1 = src[1]; pf2 = src[2]; pf3 = src[3];
      if (tid < 128) psq = sg[(tid>>5)*512 + itn*32 + (tid&31)];
    }
    #pragma unroll
    for (int jb = 0; jb < 8; jb++){
      int brow = jb*16 + (lane & 15);
      bf16x8 B0 = *(const bf16x8*)SWZ16(xjb, brow, 7,      (lane>>4)*16);
      bf16x8 B1 = *(const bf16x8*)SWZ16(xjb, brow, 7, 64 + (lane>>4)*16);
      f32x4 acc = {0.f, 0.f, 0.f, 0.f};
      acc = __builtin_amdgcn_mfma_f32_16x16x32_bf16(A0, B0, acc, 0, 0, 0);
      acc = __builtin_amdgcn_mfma_f32_16x16x32_bf16(A1, B1, acc, 0, 0, 0);
      int col = jb*16 + (lane & 15);
      float sqv = sqs[col];
      int rbase = rw + (lane>>4)*4;
      #pragma unroll
      for (int v=0; v<4; v++){
        // sortable u16 encode of f = -2*dot + sqj  (top 16 bits of sign-flipped f32)
        float f = fmaf(acc[v], -2.f, sqv);
        unsigned u = __float_as_uint(f);
        unsigned t2 = ((unsigned)((int)u >> 31)) | 0x8000u;
        *SWZ16(Dt, rbase + v, 8, col*2) = (unsigned short)((u >> 16) ^ t2);
      }
    }
    __syncthreads();
    if (it == 0){
      // warm start: sort this lane's 32 keys (bitonic, registers), kb = smallest 24
      unsigned key[32];
      const char* dbase = (const char*)Dt + (prow << 8);
      unsigned m = (prow & 7) << 4;
      #pragma unroll
      for (int r4=0; r4<4; r4++){
        uint4 dv = *(const uint4*)(dbase + ((unsigned)(q*64 + r4*16) ^ m));
        int cb = q*512 + r4*8;
        key[r4*8+0] = (dv.x << 16) + (unsigned)(cb + 0);
        key[r4*8+1] = (dv.x & 0xFFFF0000u) | (unsigned)(cb + 1);
        key[r4*8+2] = (dv.y << 16) + (unsigned)(cb + 2);
        key[r4*8+3] = (dv.y & 0xFFFF0000u) | (unsigned)(cb + 3);
        key[r4*8+4] = (dv.z << 16) + (unsigned)(cb + 4);
        key[r4*8+5] = (dv.z & 0xFFFF0000u) | (unsigned)(cb + 5);
        key[r4*8+6] = (dv.w << 16) + (unsigned)(cb + 6);
        key[r4*8+7] = (dv.w & 0xFFFF0000u) | (unsigned)(cb + 7);
      }
      #pragma unroll
      for (int k2 = 2; k2 <= 32; k2 <<= 1){
        #pragma unroll
        for (int j2 = k2>>1; j2 > 0; j2 >>= 1){
          #pragma unroll
          for (int i2 = 0; i2 < 32; i2++){
            int ixj = i2 ^ j2;
            if (ixj > i2){
              unsigned a = key[i2], b = key[ixj];
              unsigned lo = a < b ? a : b;
              unsigned hi = a < b ? b : a;
              bool up = ((i2 & k2) == 0);
              key[i2]  = up ? lo : hi;
              key[ixj] = up ? hi : lo;
            }
          }
        }
      }
      #pragma unroll
      for (int t=0;t<KK;t++) kb[t] = key[t];
      kbLast = kb[KK-1];
    } else {
      int jbase0 = q*512 + it*32;
      const char* dbase = (const char*)Dt + (prow << 8);
      unsigned m = (prow & 7) << 4;
      #pragma unroll
      for (int r4=0; r4<4; r4++){
        uint4 dv = *(const uint4*)(dbase + ((unsigned)(q*64 + r4*16) ^ m));
        int cb = jbase0 + r4*8;
        unsigned k0 = (dv.x << 16) + (unsigned)(cb + 0);
        unsigned k1 = (dv.x & 0xFFFF0000u) | (unsigned)(cb + 1);
        unsigned k2v = (dv.y << 16) + (unsigned)(cb + 2);
        unsigned k3 = (dv.y & 0xFFFF0000u) | (unsigned)(cb + 3);
        unsigned k4 = (dv.z << 16) + (unsigned)(cb + 4);
        unsigned k5 = (dv.z & 0xFFFF0000u) | (unsigned)(cb + 5);
        unsigned k6 = (dv.w << 16) + (unsigned)(cb + 6);
        unsigned k7 = (dv.w & 0xFFFF0000u) | (unsigned)(cb + 7);
        unsigned bm[8];
        bm[0] = (k0 < kbLast) ? k0 : 0xFFFFFFFFu;
        bm[1] = (k1 < kbLast) ? k1 : 0xFFFFFFFFu;
        bm[2] = (k2v < kbLast) ? k2v : 0xFFFFFFFFu;
        bm[3] = (k3 < kbLast) ? k3 : 0xFFFFFFFFu;
        bm[4] = (k4 < kbLast) ? k4 : 0xFFFFFFFFu;
        bm[5] = (k5 < kbLast) ? k5 : 0xFFFFFFFFu;
        bm[6] = (k6 < kbLast) ? k6 : 0xFFFFFFFFu;
        bm[7] = (k7 < kbLast) ? k7 : 0xFFFFFFFFu;
        unsigned mn01 = bm[0] < bm[1] ? bm[0] : bm[1];
        unsigned mn23 = bm[2] < bm[3] ? bm[2] : bm[3];
        unsigned mn45 = bm[4] < bm[5] ? bm[4] : bm[5];
        unsigned mn67 = bm[6] < bm[7] ? bm[6] : bm[7];
        unsigned mn03 = mn01 < mn23 ? mn01 : mn23;
        unsigned mn47 = mn45 < mn67 ? mn45 : mn67;
        unsigned mn = mn03 < mn47 ? mn03 : mn47;
        if (__any(mn != 0xFFFFFFFFu)) KNN_MFLUSH(bm);
      }
    }
    if (itn < 16){
      *(uint4*)SWZ16(xjb, jr, 7, half*64 +  0) = pf0;
      *(uint4*)SWZ16(xjb, jr, 7, half*64 + 16) = pf1;
      *(uint4*)SWZ16(xjb, jr, 7, half*64 + 32) = pf2;
      *(uint4*)SWZ16(xjb, jr, 7, half*64 + 48) = pf3;
      if (tid < 128) sqs[tid] = psq;
    }
    __syncthreads();
  }
  size_t base = (size_t)(g*Ng + r0 + prow)*96 + q*24;
  #pragma unroll
  for (int t=0;t<KK;t++)
    cand[base + t] = (unsigned short)(kb[t] & 2047u);
}

// ---------- exact rerank v7: all-24-in-flight + sqj from precomputed SQ[j]
//   R16 counters: 53% VALUBusy x 146us ~ 77us pure VALU; half of it was
//   recomputing |xj|^2 which decode_gemm already wrote to SQ. dist =
//   fmaf(dot,-2,SQ[j]) removes 96 of ~230 VALU ops + 2 shuffles/candidate.
//   (1-ulp summation-order diff vs chunked sqj: distances differ at 1e-3
//   scale between distinct points -> selection unaffected.)
//   [R14 lesson intact: launch_bounds stays (256,2); never min-waves>=3 here.]
__global__ __launch_bounds__(256,2) void rerank_kernel(const float* __restrict__ x,
        const float* __restrict__ sq,
        const unsigned short* __restrict__ cand, int* __restrict__ idx){
  __shared__ __align__(16) unsigned long long ks[4][96];
  int tid = threadIdx.x;
  int lane = tid & 63, w = tid >> 6;
  int bid = ((blockIdx.x & 7) << 11) | (blockIdx.x >> 3);   // XCD-chunked (16384 wg)
  int row = bid*4 + w;
  int g = row >> 11;
  const float* xg = x + (size_t)g*Ng*Hd;
  int chunk = lane & 3;        // 16B chunk within a row
  int cg = lane >> 2;          // candidate group 0..15
  const float* xr = x + (size_t)row*Hd;
  float4 xc[4];
  #pragma unroll
  for (int it2=0; it2<4; it2++) xc[it2] = *(const float4*)(xr + 16*it2 + 4*chunk);

  int js[6];
  #pragma unroll
  for (int p=0; p<6; p++) js[p] = cand[(size_t)row*96 + p*16 + cg];
  const float* sg = sq + (size_t)g*Ng;
  float sqv[6];
  #pragma unroll
  for (int p=0; p<6; p++) sqv[p] = sg[js[p]];

  // phase 1: issue all 24 gathers (static indices -> registers, deep MLP)
  float4 bb[6][4];
  #pragma unroll
  for (int p=0; p<6; p++){
    const float* xj = xg + (size_t)js[p]*Hd;
    #pragma unroll
    for (int it2=0; it2<4; it2++) bb[p][it2] = *(const float4*)(xj + 16*it2 + 4*chunk);
  }
  // phase 2: reduce (dot only; sqj comes from SQ)
  #pragma unroll
  for (int p=0; p<6; p++){
    float dot = 0.f;
    #pragma unroll
    for (int it2=0; it2<4; it2++){
      float4 b = bb[p][it2];
      float4 a = xc[it2];
      dot = fmaf(a.x, b.x, dot); dot = fmaf(a.y, b.y, dot);
      dot = fmaf(a.z, b.z, dot); dot = fmaf(a.w, b.w, dot);
    }
    dot += __shfl_xor(dot, 1, 64); dot += __shfl_xor(dot, 2, 64);
    if (chunk == 0){
      float dist = fmaf(dot, -2.f, sqv[p]);   // row-constant +sq_i dropped (order-invariant)
      ks[w][p*16 + cg] = ((unsigned long long)enc_f32(dist) << 32) | (unsigned)js[p];
    }
  }
  __syncthreads();
  unsigned long long k0 = ks[w][lane];
  unsigned long long k1 = (lane < 32) ? ks[w][64 + lane] : ~0ULL;
  int r0 = 0, r1 = 0;
  #pragma unroll
  for (int c=0;c<96;c+=2){
    unsigned long long a = ks[w][c], b = ks[w][c+1];
    r0 += (a < k0) + (b < k0);
    r1 += (a < k1) + (b < k1);
  }
  if (r0 < Kn) idx[(size_t)row*Kn + r0] = g*Ng + (int)(k0 & 2047ULL);
  if (lane < 32 && r1 < Kn) idx[(size_t)row*Kn + r1] = g*Ng + (int)(k1 & 2047ULL);
}

// ---------- dynamic EdgeConv stage 2 v2: split-bf16 MFMA GEMM (bf16x3)
__global__ __launch_bounds__(256,3) void emsg_kernel(
    const int* __restrict__ srcl,
    const float* __restrict__ P, const float* __restrict__ Q,
    const float* __restrict__ b1, const float* __restrict__ w2,
    unsigned int* __restrict__ enc){
  __shared__ __align__(16) char smem[49152];
  unsigned short* Ah = (unsigned short*)smem;            // [128][64] bf16 swz, 16384
  unsigned short* Al = (unsigned short*)(smem + 16384);  // 16384
  unsigned short* Wh = (unsigned short*)(smem + 32768);  // [64 n][64 k] bf16 swz, 8192
  unsigned short* Wl = (unsigned short*)(smem + 40960);  // 8192
  float* p0 = (float*)smem;                              // [64][33] f32 overlay on Ah/Al
  float* p1 = (float*)(smem + 8448);
  int tid = threadIdx.x;
  int lane = tid & 63, w = tid >> 6;
  int e0 = ((blockIdx.x & 7)*640 + (blockIdx.x >> 3))*256;   // XCD-chunked (5120 wg)

  // ---- stage W2 hi/lo transposed [n][k] (once; n = tid&63, k = z*4 + tid>>6)
  #pragma unroll
  for (int z = 0; z < 16; z++){
    int idx = z*256 + tid;
    int k = idx >> 6, n = idx & 63;
    float f = w2[idx];
    unsigned short h = bf16rne(f);
    float fh = __uint_as_float((unsigned)h << 16);
    unsigned short l = bf16rne(f - fh);
    *SWZ16(Wh, n, 7, k*2) = h;
    *SWZ16(Wl, n, 7, k*2) = l;
  }

  #pragma unroll 1
  for (int hh = 0; hh < 2; hh++){
    int eh0 = e0 + hh*128;
    __syncthreads();          // prev-half p-reads done; W stage visible
    // ---- stage A = relu(P[i]+Q[j]+b1) -> bf16 hi/lo (thread: edge tid>>1, k-half (tid&1)*32)
    {
      int el = tid >> 1, kh = (tid & 1) * 32;
      int e = eh0 + el;
      int i = e / Kn;
      int j = srcl[e];
      const float* Pr = P + (size_t)i*Hd + kh;
      const float* Qr = Q + (size_t)j*Hd + kh;
      const float* Br = b1 + kh;
      #pragma unroll
      for (int m = 0; m < 4; m++){
        float4 pa = ((const float4*)Pr)[2*m], pb = ((const float4*)Pr)[2*m+1];
        float4 qa = ((const float4*)Qr)[2*m], qb = ((const float4*)Qr)[2*m+1];
        float4 ba = ((const float4*)Br)[2*m], bbv = ((const float4*)Br)[2*m+1];
        float a[8];
        a[0]=fmaxf(pa.x+qa.x+ba.x,0.f);  a[1]=fmaxf(pa.y+qa.y+ba.y,0.f);
        a[2]=fmaxf(pa.z+qa.z+ba.z,0.f);  a[3]=fmaxf(pa.w+qa.w+ba.w,0.f);
        a[4]=fmaxf(pb.x+qb.x+bbv.x,0.f); a[5]=fmaxf(pb.y+qb.y+bbv.y,0.f);
        a[6]=fmaxf(pb.z+qb.z+bbv.z,0.f); a[7]=fmaxf(pb.w+qb.w+bbv.w,0.f);
        unsigned hw[4], lw[4];
        #pragma unroll
        for (int t=0;t<4;t++){
          unsigned short h0 = bf16rne(a[2*t]);
          unsigned short h1 = bf16rne(a[2*t+1]);
          float f0 = __uint_as_float((unsigned)h0 << 16);
          float f1 = __uint_as_float((unsigned)h1 << 16);
          unsigned short l0 = bf16rne(a[2*t] - f0);
          unsigned short l1 = bf16rne(a[2*t+1] - f1);
          hw[t] = (unsigned)h0 | ((unsigned)h1 << 16);
          lw[t] = (unsigned)l0 | ((unsigned)l1 << 16);
        }
        uint4 hv = {hw[0], hw[1], hw[2], hw[3]};
        uint4 lv = {lw[0], lw[1], lw[2], lw[3]};
        *(uint4*)SWZ16(Ah, el, 7, (kh + 8*m)*2) = hv;
        *(uint4*)SWZ16(Al, el, 7, (kh + 8*m)*2) = lv;
      }
    }
    __syncthreads();
    // ---- MFMA: wave w computes rows [w*32, w*32+32) x 64 cols
    bf16x8 Af[2][2], Lf[2][2];
    #pragma unroll
    for (int mt=0; mt<2; mt++)
      #pragma unroll
      for (int s=0; s<2; s++){
        int row = w*32 + mt*16 + (lane & 15);
        Af[mt][s] = *(const bf16x8*)SWZ16(Ah, row, 7, (s*32 + (lane>>4)*8)*2);
        Lf[mt][s] = *(const bf16x8*)SWZ16(Al, row, 7, (s*32 + (lane>>4)*8)*2);
      }
    f32x4 acc[2][4];
    #pragma unroll
    for (int mt=0; mt<2; mt++)
      #pragma unroll
      for (int nt=0; nt<4; nt++)
        acc[mt][nt] = (f32x4){0.f,0.f,0.f,0.f};
    #pragma unroll
    for (int nt=0; nt<4; nt++){
      int n = nt*16 + (lane & 15);
      bf16x8 Bh0 = *(const bf16x8*)SWZ16(Wh, n, 7, ((lane>>4)*8)*2);
      bf16x8 Bh1 = *(const bf16x8*)SWZ16(Wh, n, 7, (32 + (lane>>4)*8)*2);
      bf16x8 Bl0 = *(const bf16x8*)SWZ16(Wl, n, 7, ((lane>>4)*8)*2);
      bf16x8 Bl1 = *(const bf16x8*)SWZ16(Wl, n, 7, (32 + (lane>>4)*8)*2);
      #pragma unroll
      for (int mt=0; mt<2; mt++){
        f32x4 a_ = acc[mt][nt];
        a_ = __builtin_amdgcn_mfma_f32_16x16x32_bf16(Af[mt][0], Bh0, a_, 0, 0, 0);
        a_ = __builtin_amdgcn_mfma_f32_16x16x32_bf16(Af[mt][1], Bh1, a_, 0, 0, 0);
        a_ = __builtin_amdgcn_mfma_f32_16x16x32_bf16(Af[mt][0], Bl0, a_, 0, 0, 0);
        a_ = __builtin_amdgcn_mfma_f32_16x16x32_bf16(Af[mt][1], Bl1, a_, 0, 0, 0);
        a_ = __builtin_amdgcn_mfma_f32_16x16x32_bf16(Lf[mt][0], Bh0, a_, 0, 0, 0);
        a_ = __builtin_amdgcn_mfma_f32_16x16x32_bf16(Lf[mt][1], Bh1, a_, 0, 0, 0);
        acc[mt][nt] = a_;
      }
    }
    __syncthreads();          // Ah/Al dead -> p0/p1 overlay
    // ---- p-writes: 4-row chunks, <=2 nodes per chunk (4 < Kn)
    #pragma unroll
    for (int mt=0; mt<2; mt++){
      int rb = w*32 + mt*16 + (lane>>4)*4;
      int rbg = eh0 + rb;
      int nd0 = rbg / Kn;
      int split = (nd0+1)*Kn - rbg; if (split > 4) split = 4;
      int cm = rb >> 2;
      #pragma unroll
      for (int nt=0; nt<4; nt++){
        int ch = nt*16 + (lane & 15);
        float s0v = -INFINITY, s1v = -INFINITY;
        #pragma unroll
        for (int v=0; v<4; v++){
          float val = acc[mt][nt][v];
          if (v < split) s0v = fmaxf(s0v, val); else s1v = fmaxf(s1v, val);
        }
        p0[ch*33 + cm] = s0v;
        p1[ch*33 + cm] = s1v;
      }
    }
    __syncthreads();
    // ---- reduce + atomicMax
    int nfirst = eh0 / Kn;
    int ncnt = (eh0 + 127) / Kn - nfirst + 1;
    int ch = tid & 63;
    for (int ln = tid >> 6; ln < ncnt; ln += 4){
      int nd = nfirst + ln;
      int glo = nd*Kn;      if (glo < eh0)     glo = eh0;
      int ghi = nd*Kn + Kn; if (ghi > eh0+128) ghi = eh0+128;
      int mlo = (glo - eh0) >> 2, mhi = (ghi - 1 - eh0) >> 2;
      float v = -INFINITY;
      for (int mm = mlo; mm <= mhi; mm++){
        int bn = (eh0 + 4*mm) / Kn;
        if (bn == nd)     v = fmaxf(v, p0[ch*33 + mm]);
        if (bn + 1 == nd) v = fmaxf(v, p1[ch*33 + mm]);
      }
      atomicMax(&enc[(size_t)nd*Hd + ch], enc_f32(v));
    }
  }
}

// ---------- final: fused decode(+b2, no ELU) from ENC + linear head
__global__ __launch_bounds__(64) void final_kernel(const unsigned int* __restrict__ enc,
        const float* __restrict__ b2,
        const float* __restrict__ w, const float* __restrict__ bias,
        float* __restrict__ out){
  __shared__ float xs[Hd];
  int c = threadIdx.x;
  float wc[Hd];
  float bc = 0.f;
  if (c < Cd){
    #pragma unroll
    for (int d=0; d<Hd; d++) wc[d] = w[d*Cd + c];
    bc = bias[c];
  }
  float b2c = b2[c];
  for (int i = blockIdx.x; i < BNn; i += gridDim.x){
    __syncthreads();
    unsigned int e = enc[(size_t)i*Hd + c];
    unsigned int bits = (e & 0x80000000u) ? (e ^ 0x80000000u) : ~e;
    float f = __uint_as_float(bits);
    if (isfinite(f)) f += b2c; else f = 0.f;
    xs[c] = f;
    __syncthreads();
    if (c < Cd){
      float s = bc;
      #pragma unroll
      for (int d=0; d<Hd; d++) s = fmaf(xs[d], wc[d], s);
      out[(size_t)i*Cd + c] = s;
    }
  }
}

extern "C" void kernel_launch(void* const* d_in, const int* in_sizes, int n_in,
                              void* d_out, int out_size, void* d_ws, size_t ws_size,
                              hipStream_t stream){
  const float* x0   = (const float*)d_in[0];
  const int*   ei   = (const int*)d_in[1];
  const float* c1w1 = (const float*)d_in[3];
  const float* c1b1 = (const float*)d_in[4];
  const float* c1w2 = (const float*)d_in[5];
  const float* c1b2 = (const float*)d_in[6];
  const float* d1w1 = (const float*)d_in[7];
  const float* d1b1 = (const float*)d_in[8];
  const float* d1w2 = (const float*)d_in[9];
  const float* d1b2 = (const float*)d_in[10];
  const float* d2w1 = (const float*)d_in[11];
  const float* d2b1 = (const float*)d_in[12];
  const float* d2w2 = (const float*)d_in[13];
  const float* d2b2 = (const float*)d_in[14];
  const float* linw = (const float*)d_in[15];
  const float* linb = (const float*)d_in[16];
  float* out = (float*)d_out;

  char* ws = (char*)d_ws;
  size_t off = 0;
  auto alloc = [&](size_t bytes)->char*{
    char* p = ws + off; off += (bytes + 255) & ~(size_t)255; return p;
  };
  float*        X    = (float*)alloc(sizeof(float)*(size_t)BNn*Hd);
  float*        P    = (float*)alloc(sizeof(float)*(size_t)BNn*Hd);
  float*        Q    = (float*)alloc(sizeof(float)*(size_t)BNn*Hd);
  float*        H2   = (float*)alloc(sizeof(float)*(size_t)BNn*Hd);  // aliases XB, ENID
  unsigned int* ENC  = (unsigned int*)alloc(sizeof(unsigned)*(size_t)BNn*Hd); // aliases CAND
  int*          SHRD = (int*)alloc(sizeof(int)*(size_t)En);   // CSRC, later IDX
  int*          DEG  = (int*)alloc(sizeof(int)*BNn);
  int*          RPTR = (int*)alloc(sizeof(int)*(BNn+1));
  int*          CUR  = (int*)alloc(sizeof(int)*BNn);
  float*        SQ   = (float*)alloc(sizeof(float)*BNn);
  float*        WPQ0 = (float*)alloc(sizeof(float)*3*128);
  float*        WPQ1 = (float*)alloc(sizeof(float)*64*128);
  float*        WPQ2 = (float*)alloc(sizeof(float)*64*128);
  int*            CSRC = SHRD;
  int*            IDX  = SHRD;
  int*            ENID = (int*)H2;
  unsigned short* XB   = (unsigned short*)H2;
  unsigned short* CAND = (unsigned short*)ENC;
  (void)ws_size; (void)in_sizes; (void)n_in; (void)out_size;

  // static EdgeConv: CSR sort + edge-batched MFMA GEMM + run-max
  prep_w_kernel<<<BNn/256, 256, 0, stream>>>(c1w1, d1w1, d2w1, WPQ0, WPQ1, WPQ2, DEG);
  count_kernel<<<En/256, 256, 0, stream>>>(ei, DEG);
  gemm_pq_kernel<3><<<BNn/8, 128, 0, stream>>>(x0, WPQ0, P, Q);
  scan_kernel<<<1, 1024, 0, stream>>>(DEG, RPTR, CUR);
  scatter_kernel<<<En/256, 256, 0, stream>>>(ei, CUR, CSRC, ENID);
  init_enc_kernel<<<BNn*Hd/256, 256, 0, stream>>>(ENC);
  econv_gemm_kernel<<<En/256, 256, 0, stream>>>(CSRC, ENID, P, Q, c1b1, c1w2, ENC);

  // dynamic layer 1 (fused decode+gemm re-arms ENC -> no init_enc)
  decode_gemm_pq_kernel<<<BNn/8, 128, 0, stream>>>(ENC, c1b2, WPQ1, X, SQ, XB, P, Q);
  knn_kernel<<<Bg*32, 256, 0, stream>>>(XB, SQ, CAND);
  rerank_kernel<<<BNn/4, 256, 0, stream>>>(X, SQ, CAND, IDX);
  emsg_kernel<<<En/256, 256, 0, stream>>>(IDX, P, Q, d1b1, d1w2, ENC);

  // dynamic layer 2
  decode_gemm_pq_kernel<<<BNn/8, 128, 0, stream>>>(ENC, d1b2, WPQ2, X, SQ, XB, P, Q);
  knn_kernel<<<Bg*32, 256, 0, stream>>>(XB, SQ, CAND);
  rerank_kernel<<<BNn/4, 256, 0, stream>>>(X, SQ, CAND, IDX);
  emsg_kernel<<<En/256, 256, 0, stream>>>(IDX, P, Q, d2b1, d2w2, ENC);

  // final: fused decode + linear head
  final_kernel<<<8192, 64, 0, stream>>>(ENC, d2b2, linw, linb, out);
}